// Round 1
// baseline (592.355 us; speedup 1.0000x reference)
//
#include <hip/hip_runtime.h>
#include <cstdint>
#include <cstddef>

#define BB 16
#define CC 256
#define NP 1024   // H*W
#define ADIM 16
#define SCH 32

// ---------------- SE: per-(b,c) spatial mean ----------------
__global__ __launch_bounds__(256)
void se_mean_kernel(const float* __restrict__ x, float* __restrict__ s_mean) {
    int bc = blockIdx.x;
    const float* p = x + (size_t)bc * NP;
    int t = threadIdx.x;
    float v = 0.f;
#pragma unroll
    for (int i = 0; i < NP / 256; ++i) v += p[t + i * 256];
#pragma unroll
    for (int off = 32; off; off >>= 1) v += __shfl_down(v, off, 64);
    __shared__ float red[4];
    if ((t & 63) == 0) red[t >> 6] = v;
    __syncthreads();
    if (t == 0) s_mean[bc] = (red[0] + red[1] + red[2] + red[3]) * (1.0f / NP);
}

// ---------------- SE: fc1+relu, fc2+sigmoid (tiny) ----------------
__global__ __launch_bounds__(256)
void se_mlp_kernel(const float* __restrict__ s_mean,
                   const float* __restrict__ fc1_w, const float* __restrict__ fc1_b,
                   const float* __restrict__ fc2_w, const float* __restrict__ fc2_b,
                   float* __restrict__ sig) {
    int b = blockIdx.x;
    __shared__ float sm[CC];
    __shared__ float h1[64];
    int t = threadIdx.x;
    sm[t] = s_mean[b * CC + t];
    __syncthreads();
    if (t < 64) {
        float acc = fc1_b[t];
        for (int c = 0; c < CC; ++c) acc += fc1_w[t * CC + c] * sm[c];
        h1[t] = fmaxf(acc, 0.f);
    }
    __syncthreads();
    float acc = fc2_b[t];
#pragma unroll 8
    for (int c = 0; c < 64; ++c) acc += fc2_w[t * 64 + c] * h1[c];
    sig[b * CC + t] = 1.f / (1.f + __expf(-acc));
}

// ---------------- xg = x * sig (broadcast per channel) ----------------
__global__ __launch_bounds__(256)
void scale_kernel(const float* __restrict__ x, const float* __restrict__ sig,
                  float* __restrict__ yg) {
    size_t i = ((size_t)blockIdx.x * 256 + threadIdx.x) * 4;
    float4 xv = *(const float4*)(x + i);
    float sc = sig[i >> 10];   // NP=1024 floats per channel row
    float4 o;
    o.x = xv.x * sc; o.y = xv.y * sc; o.z = xv.z * sc; o.w = xv.w * sc;
    *(float4*)(yg + i) = o;
}

// ---------------- small conv1x1 (qkv / proj) ----------------
template <int OC, int IC>
__global__ __launch_bounds__(256)
void conv1x1_small_kernel(const float* __restrict__ X, size_t x_bstride,
                          const float* __restrict__ W, const float* __restrict__ bias,
                          float* __restrict__ Y, size_t y_bstride) {
    // grid: (NP/128, B)
    int nt = blockIdx.x, b = blockIdx.y;
    const float* Xb = X + (size_t)b * x_bstride + nt * 128;
    float* Yb = Y + (size_t)b * y_bstride + nt * 128;
    __shared__ __align__(16) float xs[IC][128];
    __shared__ float ws[OC * IC];
    int t = threadIdx.x;
    for (int e = t * 4; e < IC * 128; e += 1024) {
        int c = e >> 7, nn = e & 127;
        *(float4*)&xs[c][nn] = *(const float4*)&Xb[(size_t)c * NP + nn];
    }
    for (int e = t; e < OC * IC; e += 256) ws[e] = W[e];
    __syncthreads();
    int nn = t & 127;
    for (int oc = t >> 7; oc < OC; oc += 2) {
        float acc = bias[oc];
#pragma unroll
        for (int c = 0; c < IC; ++c) acc += ws[oc * IC + c] * xs[c][nn];
        Yb[(size_t)oc * NP + nn] = acc;
    }
}

// ---------------- attention: flash-style, one block per 64 queries ----------------
__global__ __launch_bounds__(256)
void attn_kernel(const float* __restrict__ qkv, float* __restrict__ attno) {
    int b = blockIdx.x >> 4;
    int q0 = (blockIdx.x & 15) * 64;
    const float* qb = qkv + (size_t)b * 64 * NP;
    __shared__ __align__(16) float k_s[16][128];
    __shared__ __align__(16) float v_s[32][128];
    __shared__ float red_max[4][64];
    __shared__ float red_sum[4][64];
    __shared__ float red_acc[4][64][33];   // +1 pad: conflict-free epilogue
    __shared__ float fsc[4][64];
    __shared__ float fsum[64];
    int t = threadIdx.x;
    int qi = t & 63, g = t >> 6;

    float qreg[16];
#pragma unroll
    for (int c = 0; c < 16; ++c) qreg[c] = qb[c * NP + q0 + qi] * 0.25f;  // AD^-0.5 folded in

    float lmax = -1e30f, lsum = 0.f;
    float acc[32];
#pragma unroll
    for (int c = 0; c < 32; ++c) acc[c] = 0.f;

    for (int m0 = 0; m0 < NP; m0 += 128) {
        __syncthreads();
        for (int e = t; e < 512; e += 256) {           // k tile 16x128
            int c = e >> 5, mm = (e & 31) * 4;
            *(float4*)&k_s[c][mm] = *(const float4*)&qb[(size_t)(16 + c) * NP + m0 + mm];
        }
        for (int e = t; e < 1024; e += 256) {          // v tile 32x128
            int c = e >> 5, mm = (e & 31) * 4;
            *(float4*)&v_s[c][mm] = *(const float4*)&qb[(size_t)(32 + c) * NP + m0 + mm];
        }
        __syncthreads();
        int mlo = g * 32;
        for (int mm = mlo; mm < mlo + 32; ++mm) {
            float s = 0.f;
#pragma unroll
            for (int c = 0; c < 16; ++c) s += qreg[c] * k_s[c][mm];
            if (s > lmax) {
                float r = __expf(lmax - s);
                lsum *= r;
#pragma unroll
                for (int c = 0; c < 32; ++c) acc[c] *= r;
                lmax = s;
            }
            float p = __expf(s - lmax);
            lsum += p;
#pragma unroll
            for (int c = 0; c < 32; ++c) acc[c] += p * v_s[c][mm];
        }
    }
    red_max[g][qi] = lmax;
    red_sum[g][qi] = lsum;
#pragma unroll
    for (int c = 0; c < 32; ++c) red_acc[g][qi][c] = acc[c];
    __syncthreads();
    if (t < 64) {
        float m0_ = red_max[0][t], m1 = red_max[1][t], m2 = red_max[2][t], m3 = red_max[3][t];
        float gm = fmaxf(fmaxf(m0_, m1), fmaxf(m2, m3));
        float e0 = __expf(m0_ - gm), e1 = __expf(m1 - gm);
        float e2 = __expf(m2 - gm), e3 = __expf(m3 - gm);
        fsc[0][t] = e0; fsc[1][t] = e1; fsc[2][t] = e2; fsc[3][t] = e3;
        fsum[t] = red_sum[0][t] * e0 + red_sum[1][t] * e1 + red_sum[2][t] * e2 + red_sum[3][t] * e3;
    }
    __syncthreads();
    for (int e = t; e < 32 * 64; e += 256) {
        int c = e >> 6, qq = e & 63;
        float val = (red_acc[0][qq][c] * fsc[0][qq] + red_acc[1][qq][c] * fsc[1][qq] +
                     red_acc[2][qq][c] * fsc[2][qq] + red_acc[3][qq][c] * fsc[3][qq]) / fsum[qq];
        attno[((size_t)b * 32 + c) * NP + q0 + qq] = val;
    }
}

// ---------------- tiled fp32 GEMM for the 1x1 convs (FFN) ----------------
// Y[b][o][n] = bias[o] + sum_c W[o][c] * X[b][c][n], per-batch column layout.
template <int K, bool RELU>
__global__ __launch_bounds__(256)
void gemm1x1_kernel(const float* __restrict__ W, const float* __restrict__ bias,
                    const float* __restrict__ X, float* __restrict__ Y, int M) {
    // grid: (M/64, nbatch, NP/64)
    int mt = blockIdx.x, b = blockIdx.y, nt = blockIdx.z;
    const float* Xb = X + (size_t)b * K * NP + nt * 64;
    float* Yb = Y + (size_t)b * M * NP + nt * 64;
    __shared__ __align__(16) float As[16][68];   // [kk][row], pad 68: aligned float4, cf banks
    __shared__ __align__(16) float Bs[16][64];   // [kk][col]
    int t = threadIdx.x;
    int tx = t & 15, ty = t >> 4;
    float acc[4][4] = {{0.f}};
    const float* Wp = W + (size_t)mt * 64 * K;
    for (int k0 = 0; k0 < K; k0 += 16) {
        __syncthreads();
        {   // A tile: 64 rows x 16 k, transpose into [kk][row]
            int row = t >> 2, kk = (t & 3) * 4;
            float4 a = *(const float4*)&Wp[(size_t)row * K + k0 + kk];
            As[kk][row] = a.x; As[kk + 1][row] = a.y;
            As[kk + 2][row] = a.z; As[kk + 3][row] = a.w;
        }
        {   // B tile: 16 k x 64 cols
            int kk = t >> 4, nn = (t & 15) * 4;
            *(float4*)&Bs[kk][nn] = *(const float4*)&Xb[(size_t)(k0 + kk) * NP + nn];
        }
        __syncthreads();
#pragma unroll
        for (int kk = 0; kk < 16; ++kk) {
            float4 av = *(const float4*)&As[kk][ty * 4];
            float4 bv = *(const float4*)&Bs[kk][tx * 4];
            acc[0][0] += av.x * bv.x; acc[0][1] += av.x * bv.y; acc[0][2] += av.x * bv.z; acc[0][3] += av.x * bv.w;
            acc[1][0] += av.y * bv.x; acc[1][1] += av.y * bv.y; acc[1][2] += av.y * bv.z; acc[1][3] += av.y * bv.w;
            acc[2][0] += av.z * bv.x; acc[2][1] += av.z * bv.y; acc[2][2] += av.z * bv.z; acc[2][3] += av.z * bv.w;
            acc[3][0] += av.w * bv.x; acc[3][1] += av.w * bv.y; acc[3][2] += av.w * bv.z; acc[3][3] += av.w * bv.w;
        }
    }
#pragma unroll
    for (int i = 0; i < 4; ++i) {
        int o = mt * 64 + ty * 4 + i;
        float bb = bias[o];
        float4 r;
        r.x = acc[i][0] + bb; r.y = acc[i][1] + bb; r.z = acc[i][2] + bb; r.w = acc[i][3] + bb;
        if (RELU) {
            r.x = fmaxf(r.x, 0.f); r.y = fmaxf(r.y, 0.f);
            r.z = fmaxf(r.z, 0.f); r.w = fmaxf(r.w, 0.f);
        }
        *(float4*)&Yb[(size_t)o * NP + tx * 4] = r;
    }
}

extern "C" void kernel_launch(void* const* d_in, const int* in_sizes, int n_in,
                              void* d_out, int out_size, void* d_ws, size_t ws_size,
                              hipStream_t stream) {
    const float* x      = (const float*)d_in[0];
    const float* fc1_w  = (const float*)d_in[1];
    const float* fc1_b  = (const float*)d_in[2];
    const float* fc2_w  = (const float*)d_in[3];
    const float* fc2_b  = (const float*)d_in[4];
    const float* qkv_w  = (const float*)d_in[5];
    const float* qkv_b  = (const float*)d_in[6];
    const float* proj_w = (const float*)d_in[7];
    const float* proj_b = (const float*)d_in[8];
    const float* ffn1_w = (const float*)d_in[9];
    const float* ffn1_b = (const float*)d_in[10];
    const float* ffn2_w = (const float*)d_in[11];
    const float* ffn2_b = (const float*)d_in[12];
    float* out = (float*)d_out;

    float* ws     = (float*)d_ws;
    float* s_mean = ws;                                // 4096
    float* sig    = s_mean + BB * CC;                  // 4096
    float* yg     = sig + BB * CC;                     // 16*256*1024  (16 MB)
    float* qkvb   = yg + (size_t)BB * CC * NP;         // 16*64*1024   (4 MB)
    float* attno  = qkvb + (size_t)BB * 64 * NP;       // 16*32*1024   (2 MB)
    float* hbuf   = attno + (size_t)BB * 32 * NP;      // 4*1024*1024  (16 MB, batch-chunked)

    se_mean_kernel<<<BB * CC, 256, 0, stream>>>(x, s_mean);
    se_mlp_kernel<<<BB, 256, 0, stream>>>(s_mean, fc1_w, fc1_b, fc2_w, fc2_b, sig);
    scale_kernel<<<(BB * CC * NP) / 1024, 256, 0, stream>>>(x, sig, yg);
    conv1x1_small_kernel<64, 32><<<dim3(NP / 128, BB), 256, 0, stream>>>(
        yg, (size_t)CC * NP, qkv_w, qkv_b, qkvb, (size_t)64 * NP);
    attn_kernel<<<BB * 16, 256, 0, stream>>>(qkvb, attno);
    conv1x1_small_kernel<32, 32><<<dim3(NP / 128, BB), 256, 0, stream>>>(
        attno, (size_t)32 * NP, proj_w, proj_b, yg, (size_t)CC * NP);

    // FFN, chunked over 4 batches at a time to bound workspace (~38 MB total).
    for (int ci = 0; ci < 4; ++ci) {
        const float* yg_c = yg + (size_t)ci * 4 * CC * NP;
        float* out_c = out + (size_t)ci * 4 * CC * NP;
        gemm1x1_kernel<256, true><<<dim3(16, 4, 16), 256, 0, stream>>>(
            ffn1_w, ffn1_b, yg_c, hbuf, 4 * CC);
        gemm1x1_kernel<1024, false><<<dim3(4, 4, 16), 256, 0, stream>>>(
            ffn2_w, ffn2_b, hbuf, out_c, CC);
    }
}

// Round 2
// 240.081 us; speedup vs baseline: 2.4673x; 2.4673x over previous
//
#include <hip/hip_runtime.h>
#include <cstdint>
#include <cstddef>

#define BB 16
#define CC 256
#define NP 1024   // H*W

typedef __attribute__((ext_vector_type(8))) short bf16x8;
typedef __attribute__((ext_vector_type(4))) float f32x4;
typedef unsigned short u16;

__device__ __forceinline__ u16 f2bf(float f) {
    union { float f; uint32_t u; } v; v.f = f;
    uint32_t u = v.u;
    return (u16)((u + 0x7FFFu + ((u >> 16) & 1u)) >> 16);   // RNE
}

// ---------------- SE: per-(b,c) spatial mean ----------------
__global__ __launch_bounds__(256)
void se_mean_kernel(const float* __restrict__ x, float* __restrict__ s_mean) {
    int bc = blockIdx.x;
    const float* p = x + (size_t)bc * NP;
    int t = threadIdx.x;
    float v = 0.f;
#pragma unroll
    for (int i = 0; i < NP / 256; ++i) v += p[t + i * 256];
#pragma unroll
    for (int off = 32; off; off >>= 1) v += __shfl_down(v, off, 64);
    __shared__ float red[4];
    if ((t & 63) == 0) red[t >> 6] = v;
    __syncthreads();
    if (t == 0) s_mean[bc] = (red[0] + red[1] + red[2] + red[3]) * (1.0f / NP);
}

// ---------------- SE: fc1+relu, fc2+sigmoid ----------------
__global__ __launch_bounds__(256)
void se_mlp_kernel(const float* __restrict__ s_mean,
                   const float* __restrict__ fc1_w, const float* __restrict__ fc1_b,
                   const float* __restrict__ fc2_w, const float* __restrict__ fc2_b,
                   float* __restrict__ sig) {
    int b = blockIdx.x;
    __shared__ float sm[CC];
    __shared__ float h1[64];
    int t = threadIdx.x;
    sm[t] = s_mean[b * CC + t];
    __syncthreads();
    if (t < 64) {
        float acc = fc1_b[t];
        for (int c = 0; c < CC; ++c) acc += fc1_w[t * CC + c] * sm[c];
        h1[t] = fmaxf(acc, 0.f);
    }
    __syncthreads();
    float acc = fc2_b[t];
#pragma unroll 8
    for (int c = 0; c < 64; ++c) acc += fc2_w[t * 64 + c] * h1[c];
    sig[b * CC + t] = 1.f / (1.f + __expf(-acc));
}

// ---------------- xg = x * sig ----------------
__global__ __launch_bounds__(256)
void scale_kernel(const float* __restrict__ x, const float* __restrict__ sig,
                  float* __restrict__ yg) {
    size_t i = ((size_t)blockIdx.x * 256 + threadIdx.x) * 4;
    float4 xv = *(const float4*)(x + i);
    float sc = sig[i >> 10];
    float4 o;
    o.x = xv.x * sc; o.y = xv.y * sc; o.z = xv.z * sc; o.w = xv.w * sc;
    *(float4*)(yg + i) = o;
}

// ---------------- small conv1x1 (qkv / proj) ----------------
template <int OC, int IC>
__global__ __launch_bounds__(256)
void conv1x1_small_kernel(const float* __restrict__ X, size_t x_bstride,
                          const float* __restrict__ W, const float* __restrict__ bias,
                          float* __restrict__ Y, size_t y_bstride) {
    int nt = blockIdx.x, b = blockIdx.y;
    const float* Xb = X + (size_t)b * x_bstride + nt * 128;
    float* Yb = Y + (size_t)b * y_bstride + nt * 128;
    __shared__ __align__(16) float xs[IC][128];
    __shared__ float ws[OC * IC];
    int t = threadIdx.x;
    for (int e = t * 4; e < IC * 128; e += 1024) {
        int c = e >> 7, nn = e & 127;
        *(float4*)&xs[c][nn] = *(const float4*)&Xb[(size_t)c * NP + nn];
    }
    for (int e = t; e < OC * IC; e += 256) ws[e] = W[e];
    __syncthreads();
    int nn = t & 127;
    for (int oc = t >> 7; oc < OC; oc += 2) {
        float acc = bias[oc];
#pragma unroll
        for (int c = 0; c < IC; ++c) acc += ws[oc * IC + c] * xs[c][nn];
        Yb[(size_t)oc * NP + nn] = acc;
    }
}

// ---------------- attention: 32 queries/block, 8-way key split ----------------
__global__ __launch_bounds__(256)
void attn_kernel(const float* __restrict__ qkv, float* __restrict__ attno) {
    int b = blockIdx.x >> 5;
    int q0 = (blockIdx.x & 31) * 32;
    const float* qb = qkv + (size_t)b * 64 * NP;
    __shared__ __align__(16) float k_s[16][128];
    __shared__ __align__(16) float v_s[32][128];
    __shared__ float red_max[8][32];
    __shared__ float red_sum[8][32];
    __shared__ float red_acc[8][32][33];
    __shared__ float fsc[8][32];
    __shared__ float fsum[32];
    int t = threadIdx.x;
    int qi = t & 31, g = t >> 5;

    float qreg[16];
#pragma unroll
    for (int c = 0; c < 16; ++c) qreg[c] = qb[c * NP + q0 + qi] * 0.25f;  // AD^-0.5 folded

    float lmax = -1e30f, lsum = 0.f;
    float acc[32];
#pragma unroll
    for (int c = 0; c < 32; ++c) acc[c] = 0.f;

    for (int m0 = 0; m0 < NP; m0 += 128) {
        __syncthreads();
        for (int e = t; e < 512; e += 256) {
            int c = e >> 5, mm = (e & 31) * 4;
            *(float4*)&k_s[c][mm] = *(const float4*)&qb[(size_t)(16 + c) * NP + m0 + mm];
        }
        for (int e = t; e < 1024; e += 256) {
            int c = e >> 5, mm = (e & 31) * 4;
            *(float4*)&v_s[c][mm] = *(const float4*)&qb[(size_t)(32 + c) * NP + m0 + mm];
        }
        __syncthreads();
        int mlo = g * 16;
        for (int mm = mlo; mm < mlo + 16; ++mm) {
            float s0 = 0.f, s1 = 0.f, s2 = 0.f, s3 = 0.f;
#pragma unroll
            for (int c = 0; c < 16; c += 4) {
                s0 += qreg[c] * k_s[c][mm];
                s1 += qreg[c + 1] * k_s[c + 1][mm];
                s2 += qreg[c + 2] * k_s[c + 2][mm];
                s3 += qreg[c + 3] * k_s[c + 3][mm];
            }
            float s = (s0 + s1) + (s2 + s3);
            if (s > lmax) {
                float r = __expf(lmax - s);
                lsum *= r;
#pragma unroll
                for (int c = 0; c < 32; ++c) acc[c] *= r;
                lmax = s;
            }
            float p = __expf(s - lmax);
            lsum += p;
#pragma unroll
            for (int c = 0; c < 32; ++c) acc[c] += p * v_s[c][mm];
        }
    }
    red_max[g][qi] = lmax;
    red_sum[g][qi] = lsum;
#pragma unroll
    for (int c = 0; c < 32; ++c) red_acc[g][qi][c] = acc[c];
    __syncthreads();
    if (t < 32) {
        float gm = -1e30f;
#pragma unroll
        for (int gg = 0; gg < 8; ++gg) gm = fmaxf(gm, red_max[gg][t]);
        float s = 0.f;
#pragma unroll
        for (int gg = 0; gg < 8; ++gg) {
            float e = __expf(red_max[gg][t] - gm);
            fsc[gg][t] = e;
            s += red_sum[gg][t] * e;
        }
        fsum[t] = s;
    }
    __syncthreads();
#pragma unroll
    for (int p = 0; p < 4; ++p) {
        int e = t + p * 256;
        int c = e >> 5, qq = e & 31;
        float val = 0.f;
#pragma unroll
        for (int gg = 0; gg < 8; ++gg) val += red_acc[gg][qq][c] * fsc[gg][qq];
        attno[((size_t)b * 32 + c) * NP + q0 + qq] = val / fsum[qq];
    }
}

// ---------------- fp32 -> bf16 flat convert ----------------
__global__ __launch_bounds__(256)
void convert_flat_kernel(const float* __restrict__ src, u16* __restrict__ dst) {
    int i = (blockIdx.x * 256 + threadIdx.x) * 4;
    float4 v = *(const float4*)(src + i);
    ushort4 o;
    o.x = f2bf(v.x); o.y = f2bf(v.y); o.z = f2bf(v.z); o.w = f2bf(v.w);
    *(ushort4*)(dst + i) = o;
}

// ---------------- yg fp32 [b][256][1024] -> ygt bf16 [b][1024][256] ----------------
__global__ __launch_bounds__(256)
void transpose_bf16_kernel(const float* __restrict__ X, u16* __restrict__ Y) {
    // grid: (NP/64, CC/64, BB)
    int nt = blockIdx.x, ct = blockIdx.y, b = blockIdx.z;
    __shared__ float tile[64][65];
    int t = threadIdx.x;
    const float* Xb = X + ((size_t)b * CC + ct * 64) * NP + nt * 64;
#pragma unroll
    for (int p = 0; p < 4; ++p) {
        int e = t + p * 256;
        int c = e >> 4, n4 = (e & 15) * 4;
        float4 v = *(const float4*)&Xb[(size_t)c * NP + n4];
        tile[c][n4] = v.x; tile[c][n4 + 1] = v.y; tile[c][n4 + 2] = v.z; tile[c][n4 + 3] = v.w;
    }
    __syncthreads();
    u16* Yb = Y + ((size_t)b * NP + nt * 64) * CC + ct * 64;
#pragma unroll
    for (int p = 0; p < 4; ++p) {
        int e = t + p * 256;
        int n = e >> 4, c4 = (e & 15) * 4;
        ushort4 o;
        o.x = f2bf(tile[c4][n]);     o.y = f2bf(tile[c4 + 1][n]);
        o.z = f2bf(tile[c4 + 2][n]); o.w = f2bf(tile[c4 + 3][n]);
        *(ushort4*)&Yb[(size_t)n * CC + c4] = o;
    }
}

// ---------------- bf16 MFMA GEMM ----------------
// D[m][n] = sum_k A[m][k] * Bt[b][n][k] (+bias[m]).  Tile 128x128, BK=32.
// LDS unpadded [row][32k]; k-chunk XOR-swizzled by (row>>1)&3 so global_load_lds
// stays legal (contiguous lane*16) AND fragment ds_read_b128 is <=2-way conflicted.
template <int K, bool RELU, bool TRANS_OUT>
__global__ __launch_bounds__(256)
void mfma_gemm_kernel(const u16* __restrict__ A,   // [M][K] bf16
                      const u16* __restrict__ Bt,  // [b][1024][K] bf16
                      const float* __restrict__ bias,
                      void* __restrict__ Yv, int M) {
    __shared__ __align__(16) u16 As[128][32];
    __shared__ __align__(16) u16 Bs[128][32];
    int mt = blockIdx.x, nt = blockIdx.y, b = blockIdx.z;
    const u16* Ab = A + (size_t)mt * 128 * K;
    const u16* Bb = Bt + ((size_t)b * 1024 + (size_t)nt * 128) * K;
    int t = threadIdx.x;
    int w = t >> 6, lane = t & 63;
    int q = lane >> 4, idx = lane & 15;
    int wr = (w >> 1) * 64, wc = (w & 1) * 64;
    int srow = lane >> 2;        // 0..15 within a 16-row staging group
    int schunk = lane & 3;

    f32x4 acc[4][4];
#pragma unroll
    for (int i = 0; i < 4; ++i)
#pragma unroll
        for (int j = 0; j < 4; ++j) { f32x4 z = {0.f, 0.f, 0.f, 0.f}; acc[i][j] = z; }

    int sw = (idx >> 1) & 3;     // read-side swizzle

    for (int k0 = 0; k0 < K; k0 += 32) {
        __syncthreads();
#pragma unroll
        for (int c = 0; c < 2; ++c) {
            int r = w * 32 + c * 16 + srow;
            int gch = schunk ^ ((r >> 1) & 3);
            __builtin_amdgcn_global_load_lds(
                (const __attribute__((address_space(1))) void*)(Ab + (size_t)r * K + k0 + gch * 8),
                (__attribute__((address_space(3))) void*)(&As[w * 32 + c * 16][0]),
                16, 0, 0);
        }
#pragma unroll
        for (int c = 0; c < 2; ++c) {
            int r = w * 32 + c * 16 + srow;
            int gch = schunk ^ ((r >> 1) & 3);
            __builtin_amdgcn_global_load_lds(
                (const __attribute__((address_space(1))) void*)(Bb + (size_t)r * K + k0 + gch * 8),
                (__attribute__((address_space(3))) void*)(&Bs[w * 32 + c * 16][0]),
                16, 0, 0);
        }
        __syncthreads();
        bf16x8 af[4], bfr[4];
#pragma unroll
        for (int i = 0; i < 4; ++i)
            af[i] = *(const bf16x8*)&As[wr + i * 16 + idx][(q ^ sw) * 8];
#pragma unroll
        for (int j = 0; j < 4; ++j)
            bfr[j] = *(const bf16x8*)&Bs[wc + j * 16 + idx][(q ^ sw) * 8];
#pragma unroll
        for (int i = 0; i < 4; ++i)
#pragma unroll
            for (int j = 0; j < 4; ++j)
                acc[i][j] = __builtin_amdgcn_mfma_f32_16x16x32_bf16(af[i], bfr[j], acc[i][j], 0, 0, 0);
    }

    if (TRANS_OUT) {
        // write bf16, transposed: Y[b][n][m]  (ReLU + bias)
        u16* Y = (u16*)Yv;
#pragma unroll
        for (int i = 0; i < 4; ++i) {
            int m0 = mt * 128 + wr + i * 16 + q * 4;
            float b0 = bias[m0], b1 = bias[m0 + 1], b2 = bias[m0 + 2], b3 = bias[m0 + 3];
#pragma unroll
            for (int j = 0; j < 4; ++j) {
                int n = nt * 128 + wc + j * 16 + idx;
                f32x4 v = acc[i][j];
                float r0 = v.x + b0, r1 = v.y + b1, r2 = v.z + b2, r3 = v.w + b3;
                if (RELU) {
                    r0 = fmaxf(r0, 0.f); r1 = fmaxf(r1, 0.f);
                    r2 = fmaxf(r2, 0.f); r3 = fmaxf(r3, 0.f);
                }
                ushort4 o;
                o.x = f2bf(r0); o.y = f2bf(r1); o.z = f2bf(r2); o.w = f2bf(r3);
                *(ushort4*)&Y[((size_t)b * NP + n) * (size_t)M + m0] = o;
            }
        }
    } else {
        // write fp32: Y[b][m][n]
        float* Y = (float*)Yv;
#pragma unroll
        for (int i = 0; i < 4; ++i) {
            int m0 = mt * 128 + wr + i * 16 + q * 4;
            float b0 = bias[m0], b1 = bias[m0 + 1], b2 = bias[m0 + 2], b3 = bias[m0 + 3];
#pragma unroll
            for (int j = 0; j < 4; ++j) {
                int n = nt * 128 + wc + j * 16 + idx;
                f32x4 v = acc[i][j];
                float* p = Y + ((size_t)b * M + m0) * NP + n;
                p[0]      = v.x + b0;
                p[NP]     = v.y + b1;
                p[2 * NP] = v.z + b2;
                p[3 * NP] = v.w + b3;
            }
        }
    }
}

extern "C" void kernel_launch(void* const* d_in, const int* in_sizes, int n_in,
                              void* d_out, int out_size, void* d_ws, size_t ws_size,
                              hipStream_t stream) {
    const float* x      = (const float*)d_in[0];
    const float* fc1_w  = (const float*)d_in[1];
    const float* fc1_b  = (const float*)d_in[2];
    const float* fc2_w  = (const float*)d_in[3];
    const float* fc2_b  = (const float*)d_in[4];
    const float* qkv_w  = (const float*)d_in[5];
    const float* qkv_b  = (const float*)d_in[6];
    const float* proj_w = (const float*)d_in[7];
    const float* proj_b = (const float*)d_in[8];
    const float* ffn1_w = (const float*)d_in[9];
    const float* ffn1_b = (const float*)d_in[10];
    const float* ffn2_w = (const float*)d_in[11];
    const float* ffn2_b = (const float*)d_in[12];
    float* out = (float*)d_out;

    // workspace layout (ht overlaps yg/qkvb/attno, which are dead by FFN1)
    float* s_mean = (float*)d_ws;                          // 4096 f
    float* sig    = s_mean + 4096;                         // 4096 f
    u16*   w1b    = (u16*)(sig + 4096);                    // 1024*256
    u16*   w2b    = w1b + 262144;                          // 256*1024
    u16*   ygt    = w2b + 262144;                          // 16*1024*256 bf16 (8 MB)
    float* yg     = (float*)(ygt + (size_t)BB * NP * CC);  // 16 MB
    float* qkvb   = yg + (size_t)BB * CC * NP;             // 4 MB
    float* attno  = qkvb + (size_t)BB * 64 * NP;           // 2 MB
    u16*   ht     = (u16*)yg;                              // 33.5 MB, overlaps dead bufs

    se_mean_kernel<<<BB * CC, 256, 0, stream>>>(x, s_mean);
    se_mlp_kernel<<<BB, 256, 0, stream>>>(s_mean, fc1_w, fc1_b, fc2_w, fc2_b, sig);
    scale_kernel<<<(BB * CC * NP) / 1024, 256, 0, stream>>>(x, sig, yg);
    convert_flat_kernel<<<256, 256, 0, stream>>>(ffn1_w, w1b);
    convert_flat_kernel<<<256, 256, 0, stream>>>(ffn2_w, w2b);
    conv1x1_small_kernel<64, 32><<<dim3(NP / 128, BB), 256, 0, stream>>>(
        yg, (size_t)CC * NP, qkv_w, qkv_b, qkvb, (size_t)64 * NP);
    attn_kernel<<<BB * 32, 256, 0, stream>>>(qkvb, attno);
    conv1x1_small_kernel<32, 32><<<dim3(NP / 128, BB), 256, 0, stream>>>(
        attno, (size_t)32 * NP, proj_w, proj_b, yg, (size_t)CC * NP);
    transpose_bf16_kernel<<<dim3(16, 4, BB), 256, 0, stream>>>(yg, ygt);

    // FFN1: h[b][n][1024] (bf16, transposed, ReLU) = ffn1_w(1024x256) @ ygt
    mfma_gemm_kernel<256, true, true><<<dim3(8, 8, BB), 256, 0, stream>>>(
        w1b, ygt, ffn1_b, (void*)ht, 1024);
    // FFN2: out[b][256][1024] (fp32) = ffn2_w(256x1024) @ ht
    mfma_gemm_kernel<1024, false, false><<<dim3(2, 8, BB), 256, 0, stream>>>(
        w2b, ht, ffn2_b, (void*)out, 256);
}

// Round 3
// 222.861 us; speedup vs baseline: 2.6580x; 1.0773x over previous
//
#include <hip/hip_runtime.h>
#include <cstdint>
#include <cstddef>

#define BB 16
#define CC 256
#define NP 1024   // H*W

typedef __attribute__((ext_vector_type(8))) short bf16x8;
typedef __attribute__((ext_vector_type(4))) float f32x4;
typedef unsigned short u16;

__device__ __forceinline__ u16 f2bf(float f) {
    union { float f; uint32_t u; } v; v.f = f;
    uint32_t u = v.u;
    return (u16)((u + 0x7FFFu + ((u >> 16) & 1u)) >> 16);   // RNE
}

// ---------------- SE fused: mean -> fc1+relu -> fc2+sigmoid ----------------
__global__ __launch_bounds__(256)
void se_kernel(const float* __restrict__ x,
               const float* __restrict__ fc1_w, const float* __restrict__ fc1_b,
               const float* __restrict__ fc2_w, const float* __restrict__ fc2_b,
               float* __restrict__ sig) {
    int b = blockIdx.x;
    __shared__ float sm[CC];
    __shared__ float h1[64];
    int t = threadIdx.x, w = t >> 6, lane = t & 63;
    const float* xb = x + (size_t)b * CC * NP;
    for (int ci = 0; ci < 64; ++ci) {
        int c = w * 64 + ci;
        const float* p = xb + (size_t)c * NP + lane * 16;
        float s = 0.f;
#pragma unroll
        for (int i = 0; i < 4; ++i) {
            float4 v = *(const float4*)(p + i * 4);
            s += (v.x + v.y) + (v.z + v.w);
        }
#pragma unroll
        for (int off = 32; off; off >>= 1) s += __shfl_down(s, off, 64);
        if (lane == 0) sm[c] = s * (1.0f / NP);
    }
    __syncthreads();
    if (t < 64) {
        float a = fc1_b[t];
        for (int c = 0; c < CC; ++c) a += fc1_w[t * CC + c] * sm[c];
        h1[t] = fmaxf(a, 0.f);
    }
    __syncthreads();
    float a = fc2_b[t];
#pragma unroll 8
    for (int c = 0; c < 64; ++c) a += fc2_w[t * 64 + c] * h1[c];
    sig[b * CC + t] = 1.f / (1.f + __expf(-a));
}

// ---------------- scale + transpose: xg fp32 [b][c<32][n] and ygt bf16 [b][n][c>=32] ----------------
__global__ __launch_bounds__(256)
void scale_transpose_kernel(const float* __restrict__ x, const float* __restrict__ sig,
                            float* __restrict__ yg32, u16* __restrict__ ygt) {
    // grid: (16 nt, 4 ct, BB)
    int nt = blockIdx.x, ct = blockIdx.y, b = blockIdx.z;
    __shared__ float tile[64][65];
    int t = threadIdx.x;
    const float* Xb = x + ((size_t)b * CC + ct * 64) * NP + nt * 64;
    float* ygb = yg32 + (size_t)b * 32 * NP + nt * 64;
#pragma unroll
    for (int p = 0; p < 4; ++p) {
        int e = t + p * 256;
        int c = e >> 4, n4 = (e & 15) * 4;
        float4 v = *(const float4*)&Xb[(size_t)c * NP + n4];
        float sc = sig[b * CC + ct * 64 + c];
        v.x *= sc; v.y *= sc; v.z *= sc; v.w *= sc;
        tile[c][n4] = v.x; tile[c][n4 + 1] = v.y; tile[c][n4 + 2] = v.z; tile[c][n4 + 3] = v.w;
        if (ct == 0 && c < 32) *(float4*)&ygb[(size_t)c * NP + n4] = v;
    }
    __syncthreads();
    u16* Yb = ygt + ((size_t)b * NP + nt * 64) * CC + ct * 64;
#pragma unroll
    for (int p = 0; p < 4; ++p) {
        int e = t + p * 256;
        int n = e >> 4, c4 = (e & 15) * 4;
        if (ct * 64 + c4 >= 32) {
            ushort4 o;
            o.x = f2bf(tile[c4][n]);     o.y = f2bf(tile[c4 + 1][n]);
            o.z = f2bf(tile[c4 + 2][n]); o.w = f2bf(tile[c4 + 3][n]);
            *(ushort4*)&Yb[(size_t)n * CC + c4] = o;
        }
    }
}

// ---------------- qkv conv: yg32 -> Qt [b][n][32] (x0.25, zero-padded), Kt [b][m][32], Vb [b][32][m] ----------------
__global__ __launch_bounds__(256)
void qkv_kernel(const float* __restrict__ yg32,
                const float* __restrict__ W, const float* __restrict__ bias,
                u16* __restrict__ Qt, u16* __restrict__ Kt, u16* __restrict__ Vb) {
    // grid: (8, BB)
    int nt = blockIdx.x, b = blockIdx.y;
    const float* Xb = yg32 + (size_t)b * 32 * NP + nt * 128;
    __shared__ __align__(16) float xs[32][128];
    __shared__ float ws[64 * 32];
    __shared__ float bs[64];
    int t = threadIdx.x;
    for (int e = t * 4; e < 32 * 128; e += 1024) {
        int c = e >> 7, nn = e & 127;
        *(float4*)&xs[c][nn] = *(const float4*)&Xb[(size_t)c * NP + nn];
    }
    for (int e = t; e < 2048; e += 256) ws[e] = W[e];
    if (t < 64) bs[t] = bias[t];
    __syncthreads();
    int nn = t & 127, g = t >> 7;
    int n = nt * 128 + nn;
    float acc[32];
#pragma unroll
    for (int oc = 0; oc < 32; ++oc) {
        int o = g * 32 + oc;
        float a = bs[o];
#pragma unroll
        for (int c = 0; c < 32; ++c) a += ws[o * 32 + c] * xs[c][nn];
        acc[oc] = a;
    }
    if (g == 0) {
        u16* qr = Qt + ((size_t)b * NP + n) * 32;
        u16* kr = Kt + ((size_t)b * NP + n) * 32;
        ushort4 z4; z4.x = 0; z4.y = 0; z4.z = 0; z4.w = 0;
#pragma unroll
        for (int j = 0; j < 16; j += 4) {
            ushort4 o4, k4;
            o4.x = f2bf(acc[j] * 0.25f);     o4.y = f2bf(acc[j + 1] * 0.25f);
            o4.z = f2bf(acc[j + 2] * 0.25f); o4.w = f2bf(acc[j + 3] * 0.25f);
            k4.x = f2bf(acc[16 + j]);     k4.y = f2bf(acc[16 + j + 1]);
            k4.z = f2bf(acc[16 + j + 2]); k4.w = f2bf(acc[16 + j + 3]);
            *(ushort4*)&qr[j] = o4;
            *(ushort4*)&kr[j] = k4;
        }
#pragma unroll
        for (int j = 16; j < 32; j += 4) { *(ushort4*)&qr[j] = z4; *(ushort4*)&kr[j] = z4; }
    } else {
        u16* vp = Vb + (size_t)b * 32 * NP + n;
#pragma unroll
        for (int c = 0; c < 32; ++c) vp[(size_t)c * NP] = f2bf(acc[c]);
    }
}

// ---------------- MFMA flash attention + fused proj ----------------
// Each wave owns 16 q-rows, sweeps all 1024 keys in 32-m strips.
__global__ __launch_bounds__(256)
void attn_mfma_kernel(const u16* __restrict__ Qt, const u16* __restrict__ Kt,
                      const u16* __restrict__ Vb,
                      const float* __restrict__ proj_w, const float* __restrict__ proj_b,
                      u16* __restrict__ ygt) {
    int b = blockIdx.x >> 4;
    int n0 = (blockIdx.x & 15) * 64;
    __shared__ __align__(16) u16 P_lds[4][16][40];   // [n][m], 80 B rows (16B-aligned)
    __shared__ float al_lds[4][16];
    __shared__ float lv_lds[4][16];
    __shared__ float O_lds[4][16][33];               // [n][c]
    __shared__ float pw_s[32][32];
    __shared__ float pb_s[32];
    int t = threadIdx.x;
    int w = t >> 6, lane = t & 63;
    int q = lane >> 4, idx = lane & 15;

    for (int e = t; e < 1024; e += 256) pw_s[e >> 5][e & 31] = proj_w[e];
    if (t < 32) pb_s[t] = proj_b[t];
    __syncthreads();

    const u16* Qb = Qt + (size_t)b * NP * 32;
    const u16* Kb = Kt + (size_t)b * NP * 32;
    const u16* Vp = Vb + (size_t)b * 32 * NP;

    int nrow = n0 + w * 16 + idx;
    bf16x8 aq = *(const bf16x8*)&Qb[(size_t)nrow * 32 + q * 8];

    f32x4 O0 = {0.f, 0.f, 0.f, 0.f}, O1 = {0.f, 0.f, 0.f, 0.f};
    float m_run[4] = {-1e30f, -1e30f, -1e30f, -1e30f};
    float l_run[4] = {0.f, 0.f, 0.f, 0.f};

    for (int m0 = 0; m0 < NP; m0 += 32) {
        bf16x8 bk0 = *(const bf16x8*)&Kb[(size_t)(m0 + idx) * 32 + q * 8];
        bf16x8 bk1 = *(const bf16x8*)&Kb[(size_t)(m0 + 16 + idx) * 32 + q * 8];
        bf16x8 va0 = *(const bf16x8*)&Vp[(size_t)idx * NP + m0 + q * 8];
        bf16x8 va1 = *(const bf16x8*)&Vp[(size_t)(16 + idx) * NP + m0 + q * 8];
        f32x4 z = {0.f, 0.f, 0.f, 0.f};
        f32x4 S0 = __builtin_amdgcn_mfma_f32_16x16x32_bf16(aq, bk0, z, 0, 0, 0);
        f32x4 S1 = __builtin_amdgcn_mfma_f32_16x16x32_bf16(aq, bk1, z, 0, 0, 0);
        float mx[4], p0[4], p1[4], alpha[4];
#pragma unroll
        for (int r = 0; r < 4; ++r) mx[r] = fmaxf(S0[r], S1[r]);
#pragma unroll
        for (int off = 1; off < 16; off <<= 1)
#pragma unroll
            for (int r = 0; r < 4; ++r) mx[r] = fmaxf(mx[r], __shfl_xor(mx[r], off, 64));
#pragma unroll
        for (int r = 0; r < 4; ++r) {
            float nm = fmaxf(m_run[r], mx[r]);
            alpha[r] = __expf(m_run[r] - nm);
            m_run[r] = nm;
            p0[r] = __expf(S0[r] - nm);
            p1[r] = __expf(S1[r] - nm);
        }
#pragma unroll
        for (int r = 0; r < 4; ++r) {
            float s = p0[r] + p1[r];
#pragma unroll
            for (int off = 1; off < 16; off <<= 1) s += __shfl_xor(s, off, 64);
            l_run[r] = l_run[r] * alpha[r] + s;
        }
#pragma unroll
        for (int r = 0; r < 4; ++r) {
            P_lds[w][q * 4 + r][idx]      = f2bf(p0[r]);
            P_lds[w][q * 4 + r][idx + 16] = f2bf(p1[r]);
        }
        if (idx == 0) {
#pragma unroll
            for (int r = 0; r < 4; ++r) al_lds[w][q * 4 + r] = alpha[r];
        }
        float an = al_lds[w][idx];   // alpha for this lane's O column n=idx (in-order wave LDS)
#pragma unroll
        for (int r = 0; r < 4; ++r) { O0[r] *= an; O1[r] *= an; }
        bf16x8 pf = *(const bf16x8*)&P_lds[w][idx][q * 8];
        O0 = __builtin_amdgcn_mfma_f32_16x16x32_bf16(va0, pf, O0, 0, 0, 0);
        O1 = __builtin_amdgcn_mfma_f32_16x16x32_bf16(va1, pf, O1, 0, 0, 0);
    }
    if (idx == 0) {
#pragma unroll
        for (int r = 0; r < 4; ++r) lv_lds[w][q * 4 + r] = l_run[r];
    }
    float linv = 1.0f / lv_lds[w][idx];
#pragma unroll
    for (int r = 0; r < 4; ++r) {
        O_lds[w][idx][q * 4 + r]      = O0[r] * linv;
        O_lds[w][idx][q * 4 + r + 16] = O1[r] * linv;
    }
    // fused proj: lane computes oc = q*4+r (+16) for n = idx
    float o0[4], o1[4];
#pragma unroll
    for (int r = 0; r < 4; ++r) { o0[r] = pb_s[q * 4 + r]; o1[r] = pb_s[q * 4 + r + 16]; }
#pragma unroll
    for (int c = 0; c < 32; ++c) {
        float xv = O_lds[w][idx][c];
#pragma unroll
        for (int r = 0; r < 4; ++r) {
            o0[r] += pw_s[q * 4 + r][c] * xv;
            o1[r] += pw_s[q * 4 + r + 16][c] * xv;
        }
    }
    u16* yrow = ygt + ((size_t)b * NP + nrow) * CC;
    ushort4 w0, w1;
    w0.x = f2bf(o0[0]); w0.y = f2bf(o0[1]); w0.z = f2bf(o0[2]); w0.w = f2bf(o0[3]);
    w1.x = f2bf(o1[0]); w1.y = f2bf(o1[1]); w1.z = f2bf(o1[2]); w1.w = f2bf(o1[3]);
    *(ushort4*)&yrow[q * 4] = w0;
    *(ushort4*)&yrow[q * 4 + 16] = w1;
}

// ---------------- fp32 -> bf16 weight convert (both FFN weights, one launch) ----------------
__global__ __launch_bounds__(256)
void convert_w_kernel(const float* __restrict__ w1, u16* __restrict__ d1,
                      const float* __restrict__ w2, u16* __restrict__ d2) {
    int blk = blockIdx.x;
    const float* src = (blk < 256) ? w1 : w2;
    u16* dst = (blk < 256) ? d1 : d2;
    int i = ((blk & 255) * 256 + threadIdx.x) * 4;
    float4 v = *(const float4*)(src + i);
    ushort4 o;
    o.x = f2bf(v.x); o.y = f2bf(v.y); o.z = f2bf(v.z); o.w = f2bf(v.w);
    *(ushort4*)(dst + i) = o;
}

// ---------------- bf16 MFMA GEMM, 128x128 tile, BK=64, XOR-swizzled LDS ----------------
// D[m][n] = sum_k A[m][k] * Bt[nflat][k] (+bias[m]); N flat over (b,n).
template <int K, bool RELU, bool TRANS_OUT>
__global__ __launch_bounds__(256)
void mfma_gemm_kernel(const u16* __restrict__ A, const u16* __restrict__ Bt,
                      const float* __restrict__ bias, void* __restrict__ Yv, int M) {
    __shared__ __align__(16) u16 As[128][64];
    __shared__ __align__(16) u16 Bs[128][64];
    int mt = blockIdx.x, nt = blockIdx.y;
    const u16* Ab = A + (size_t)mt * 128 * K;
    const u16* Bb = Bt + (size_t)nt * 128 * K;
    int t = threadIdx.x;
    int w = t >> 6, lane = t & 63;
    int q = lane >> 4, idx = lane & 15;
    int wr = (w >> 1) * 64, wc = (w & 1) * 64;
    int srow = lane >> 3;       // 0..7
    int gch = (lane & 7) ^ srow;  // swizzled source chunk

    f32x4 acc[4][4];
#pragma unroll
    for (int i = 0; i < 4; ++i)
#pragma unroll
        for (int j = 0; j < 4; ++j) { f32x4 z = {0.f, 0.f, 0.f, 0.f}; acc[i][j] = z; }

    for (int k0 = 0; k0 < K; k0 += 64) {
        __syncthreads();
#pragma unroll
        for (int p = 0; p < 4; ++p) {
            int r = w * 32 + p * 8 + srow;
            __builtin_amdgcn_global_load_lds(
                (const __attribute__((address_space(1))) void*)(Ab + (size_t)r * K + k0 + gch * 8),
                (__attribute__((address_space(3))) void*)(&As[w * 32 + p * 8][0]),
                16, 0, 0);
        }
#pragma unroll
        for (int p = 0; p < 4; ++p) {
            int r = w * 32 + p * 8 + srow;
            __builtin_amdgcn_global_load_lds(
                (const __attribute__((address_space(1))) void*)(Bb + (size_t)r * K + k0 + gch * 8),
                (__attribute__((address_space(3))) void*)(&Bs[w * 32 + p * 8][0]),
                16, 0, 0);
        }
        __syncthreads();
#pragma unroll
        for (int h = 0; h < 2; ++h) {
            bf16x8 af[4], bfr[4];
#pragma unroll
            for (int i = 0; i < 4; ++i)
                af[i] = *(const bf16x8*)&As[wr + i * 16 + idx][(((q + 4 * h) ^ (idx & 7)) * 8)];
#pragma unroll
            for (int j = 0; j < 4; ++j)
                bfr[j] = *(const bf16x8*)&Bs[wc + j * 16 + idx][(((q + 4 * h) ^ (idx & 7)) * 8)];
#pragma unroll
            for (int i = 0; i < 4; ++i)
#pragma unroll
                for (int j = 0; j < 4; ++j)
                    acc[i][j] = __builtin_amdgcn_mfma_f32_16x16x32_bf16(af[i], bfr[j], acc[i][j], 0, 0, 0);
        }
    }

    if (TRANS_OUT) {
        u16* Y = (u16*)Yv;
#pragma unroll
        for (int i = 0; i < 4; ++i) {
            int m0 = mt * 128 + wr + i * 16 + q * 4;
            float b0 = bias[m0], b1 = bias[m0 + 1], b2 = bias[m0 + 2], b3 = bias[m0 + 3];
#pragma unroll
            for (int j = 0; j < 4; ++j) {
                int n = nt * 128 + wc + j * 16 + idx;
                f32x4 v = acc[i][j];
                float r0 = v.x + b0, r1 = v.y + b1, r2 = v.z + b2, r3 = v.w + b3;
                if (RELU) {
                    r0 = fmaxf(r0, 0.f); r1 = fmaxf(r1, 0.f);
                    r2 = fmaxf(r2, 0.f); r3 = fmaxf(r3, 0.f);
                }
                ushort4 o;
                o.x = f2bf(r0); o.y = f2bf(r1); o.z = f2bf(r2); o.w = f2bf(r3);
                *(ushort4*)&Y[(size_t)n * (size_t)M + m0] = o;
            }
        }
    } else {
        float* Y = (float*)Yv;
#pragma unroll
        for (int i = 0; i < 4; ++i) {
            int m0 = mt * 128 + wr + i * 16 + q * 4;
            float b0 = bias[m0], b1 = bias[m0 + 1], b2 = bias[m0 + 2], b3 = bias[m0 + 3];
#pragma unroll
            for (int j = 0; j < 4; ++j) {
                int ng = nt * 128 + wc + j * 16 + idx;
                int bb = ng >> 10, nn = ng & 1023;
                f32x4 v = acc[i][j];
                float* p = Y + ((size_t)bb * M + m0) * NP + nn;
                p[0]      = v.x + b0;
                p[NP]     = v.y + b1;
                p[2 * NP] = v.z + b2;
                p[3 * NP] = v.w + b3;
            }
        }
    }
}

extern "C" void kernel_launch(void* const* d_in, const int* in_sizes, int n_in,
                              void* d_out, int out_size, void* d_ws, size_t ws_size,
                              hipStream_t stream) {
    const float* x      = (const float*)d_in[0];
    const float* fc1_w  = (const float*)d_in[1];
    const float* fc1_b  = (const float*)d_in[2];
    const float* fc2_w  = (const float*)d_in[3];
    const float* fc2_b  = (const float*)d_in[4];
    const float* qkv_w  = (const float*)d_in[5];
    const float* qkv_b  = (const float*)d_in[6];
    const float* proj_w = (const float*)d_in[7];
    const float* proj_b = (const float*)d_in[8];
    const float* ffn1_w = (const float*)d_in[9];
    const float* ffn1_b = (const float*)d_in[10];
    const float* ffn2_w = (const float*)d_in[11];
    const float* ffn2_b = (const float*)d_in[12];
    float* out = (float*)d_out;

    // layout: [w1b 512K][w2b 512K][ygt 8M][ht 32M]; pre-FFN buffers overlap ht (dead by then)
    u16* w1b = (u16*)d_ws;
    u16* w2b = w1b + 262144;
    u16* ygt = w2b + 262144;                       // [b*1024][256] bf16
    u16* ht  = ygt + (size_t)BB * NP * CC;         // [b*1024][1024] bf16
    float* sig  = (float*)ht;                      // 16 KB
    float* yg32 = sig + BB * CC;                   // 2 MB
    u16* Qt = (u16*)(yg32 + (size_t)BB * 32 * NP); // 1 MB
    u16* Kt = Qt + (size_t)BB * NP * 32;           // 1 MB
    u16* Vb = Kt + (size_t)BB * NP * 32;           // 1 MB

    se_kernel<<<BB, 256, 0, stream>>>(x, fc1_w, fc1_b, fc2_w, fc2_b, sig);
    convert_w_kernel<<<512, 256, 0, stream>>>(ffn1_w, w1b, ffn2_w, w2b);
    scale_transpose_kernel<<<dim3(16, 4, BB), 256, 0, stream>>>(x, sig, yg32, ygt);
    qkv_kernel<<<dim3(8, BB), 256, 0, stream>>>(yg32, qkv_w, qkv_b, Qt, Kt, Vb);
    attn_mfma_kernel<<<BB * 16, 256, 0, stream>>>(Qt, Kt, Vb, proj_w, proj_b, ygt);

    // FFN1: ht[nflat][1024] bf16 (ReLU) = ffn1_w(1024x256) @ ygt
    mfma_gemm_kernel<256, true, true><<<dim3(8, 128), 256, 0, stream>>>(
        w1b, ygt, ffn1_b, (void*)ht, 1024);
    // FFN2: out[b][256][1024] fp32 = ffn2_w(256x1024) @ ht
    mfma_gemm_kernel<1024, false, false><<<dim3(2, 128), 256, 0, stream>>>(
        w2b, ht, ffn2_b, (void*)out, 256);
}

// Round 4
// 192.558 us; speedup vs baseline: 3.0762x; 1.1574x over previous
//
#include <hip/hip_runtime.h>
#include <cstdint>
#include <cstddef>

#define BB 16
#define CC 256
#define NP 1024   // H*W

typedef __attribute__((ext_vector_type(8))) short bf16x8;
typedef __attribute__((ext_vector_type(4))) float f32x4;
typedef unsigned short u16;

__device__ __forceinline__ u16 f2bf(float f) {
    union { float f; uint32_t u; } v; v.f = f;
    uint32_t u = v.u;
    return (u16)((u + 0x7FFFu + ((u >> 16) & 1u)) >> 16);   // RNE
}

// ---------------- SE mean: one block per (b,c) row ----------------
__global__ __launch_bounds__(256)
void se_mean_kernel(const float* __restrict__ x, float* __restrict__ s_mean) {
    int bc = blockIdx.x;
    const float* p = x + (size_t)bc * NP;
    int t = threadIdx.x;
    float4 v = *(const float4*)(p + t * 4);
    float s = (v.x + v.y) + (v.z + v.w);
#pragma unroll
    for (int off = 32; off; off >>= 1) s += __shfl_down(s, off, 64);
    __shared__ float red[4];
    if ((t & 63) == 0) red[t >> 6] = s;
    __syncthreads();
    if (t == 0) s_mean[bc] = (red[0] + red[1] + red[2] + red[3]) * (1.0f / NP);
}

// ---------------- SE mlp: fc1+relu -> fc2+sigmoid (tiny) ----------------
__global__ __launch_bounds__(256)
void se_mlp_kernel(const float* __restrict__ s_mean,
                   const float* __restrict__ fc1_w, const float* __restrict__ fc1_b,
                   const float* __restrict__ fc2_w, const float* __restrict__ fc2_b,
                   float* __restrict__ sig) {
    int b = blockIdx.x;
    __shared__ float sm[CC];
    __shared__ float h1[64];
    int t = threadIdx.x;
    sm[t] = s_mean[b * CC + t];
    __syncthreads();
    if (t < 64) {
        float a = fc1_b[t];
        for (int c = 0; c < CC; ++c) a += fc1_w[t * CC + c] * sm[c];
        h1[t] = fmaxf(a, 0.f);
    }
    __syncthreads();
    float a = fc2_b[t];
#pragma unroll 8
    for (int c = 0; c < 64; ++c) a += fc2_w[t * 64 + c] * h1[c];
    sig[b * CC + t] = 1.f / (1.f + __expf(-a));
}

// ---------------- scale + transpose: xg fp32 [b][c<32][n] and ygt bf16 [b][n][c>=32] ----------------
__global__ __launch_bounds__(256)
void scale_transpose_kernel(const float* __restrict__ x, const float* __restrict__ sig,
                            float* __restrict__ yg32, u16* __restrict__ ygt) {
    // grid: (16 nt, 4 ct, BB)
    int nt = blockIdx.x, ct = blockIdx.y, b = blockIdx.z;
    __shared__ float tile[64][65];
    int t = threadIdx.x;
    const float* Xb = x + ((size_t)b * CC + ct * 64) * NP + nt * 64;
    float* ygb = yg32 + (size_t)b * 32 * NP + nt * 64;
#pragma unroll
    for (int p = 0; p < 4; ++p) {
        int e = t + p * 256;
        int c = e >> 4, n4 = (e & 15) * 4;
        float4 v = *(const float4*)&Xb[(size_t)c * NP + n4];
        float sc = sig[b * CC + ct * 64 + c];
        v.x *= sc; v.y *= sc; v.z *= sc; v.w *= sc;
        tile[c][n4] = v.x; tile[c][n4 + 1] = v.y; tile[c][n4 + 2] = v.z; tile[c][n4 + 3] = v.w;
        if (ct == 0 && c < 32) *(float4*)&ygb[(size_t)c * NP + n4] = v;
    }
    __syncthreads();
    u16* Yb = ygt + ((size_t)b * NP + nt * 64) * CC + ct * 64;
#pragma unroll
    for (int p = 0; p < 4; ++p) {
        int e = t + p * 256;
        int n = e >> 4, c4 = (e & 15) * 4;
        if (ct * 64 + c4 >= 32) {
            ushort4 o;
            o.x = f2bf(tile[c4][n]);     o.y = f2bf(tile[c4 + 1][n]);
            o.z = f2bf(tile[c4 + 2][n]); o.w = f2bf(tile[c4 + 3][n]);
            *(ushort4*)&Yb[(size_t)n * CC + c4] = o;
        }
    }
}

// ---------------- qkv conv: yg32 -> Qt [b][n][32] (x0.25, zero-padded), Kt [b][m][32], Vb [b][32][m] ----------------
__global__ __launch_bounds__(256)
void qkv_kernel(const float* __restrict__ yg32,
                const float* __restrict__ W, const float* __restrict__ bias,
                u16* __restrict__ Qt, u16* __restrict__ Kt, u16* __restrict__ Vb) {
    // grid: (16, BB); block handles 64 pixels, thread = (px, oc-group of 16)
    int nt = blockIdx.x, b = blockIdx.y;
    const float* Xb = yg32 + (size_t)b * 32 * NP + nt * 64;
    __shared__ __align__(16) float xs[32][64];
    __shared__ float ws[64 * 32];
    __shared__ float bs[64];
    __shared__ float vtile[32][64];
    int t = threadIdx.x;
    for (int e = t * 4; e < 32 * 64; e += 1024) {
        int c = e >> 6, nn = e & 63;
        *(float4*)&xs[c][nn] = *(const float4*)&Xb[(size_t)c * NP + nn];
    }
    for (int e = t; e < 2048; e += 256) ws[e] = W[e];
    if (t < 64) bs[t] = bias[t];
    __syncthreads();
    int nn = t & 63, g = t >> 6;   // g: oc group of 16
    int n = nt * 64 + nn;
    float acc[16];
#pragma unroll
    for (int oc = 0; oc < 16; ++oc) {
        int o = g * 16 + oc;
        float a = bs[o];
#pragma unroll
        for (int c = 0; c < 32; ++c) a += ws[o * 32 + c] * xs[c][nn];
        acc[oc] = a;
    }
    if (g == 0) {
        u16* qr = Qt + ((size_t)b * NP + n) * 32;
        ushort4 z4; z4.x = 0; z4.y = 0; z4.z = 0; z4.w = 0;
#pragma unroll
        for (int j = 0; j < 16; j += 4) {
            ushort4 o4;
            o4.x = f2bf(acc[j] * 0.25f);     o4.y = f2bf(acc[j + 1] * 0.25f);
            o4.z = f2bf(acc[j + 2] * 0.25f); o4.w = f2bf(acc[j + 3] * 0.25f);
            *(ushort4*)&qr[j] = o4;
        }
        *(ushort4*)&qr[16] = z4; *(ushort4*)&qr[20] = z4;
        *(ushort4*)&qr[24] = z4; *(ushort4*)&qr[28] = z4;
    } else if (g == 1) {
        u16* kr = Kt + ((size_t)b * NP + n) * 32;
        ushort4 z4; z4.x = 0; z4.y = 0; z4.z = 0; z4.w = 0;
#pragma unroll
        for (int j = 0; j < 16; j += 4) {
            ushort4 k4;
            k4.x = f2bf(acc[j]);     k4.y = f2bf(acc[j + 1]);
            k4.z = f2bf(acc[j + 2]); k4.w = f2bf(acc[j + 3]);
            *(ushort4*)&kr[j] = k4;
        }
        *(ushort4*)&kr[16] = z4; *(ushort4*)&kr[20] = z4;
        *(ushort4*)&kr[24] = z4; *(ushort4*)&kr[28] = z4;
    } else {
#pragma unroll
        for (int oc = 0; oc < 16; ++oc) vtile[(g - 2) * 16 + oc][nn] = acc[oc];
    }
    __syncthreads();
    // coalesced V store: 32 rows x 64 px
    for (int e = t; e < 32 * 64; e += 256) {
        int c = e >> 6, nn2 = e & 63;
        Vb[(size_t)b * 32 * NP + (size_t)c * NP + nt * 64 + nn2] = f2bf(vtile[c][nn2]);
    }
}

// ---------------- MFMA flash attention + fused proj ----------------
__global__ __launch_bounds__(256)
void attn_mfma_kernel(const u16* __restrict__ Qt, const u16* __restrict__ Kt,
                      const u16* __restrict__ Vb,
                      const float* __restrict__ proj_w, const float* __restrict__ proj_b,
                      u16* __restrict__ ygt) {
    int b = blockIdx.x >> 4;
    int n0 = (blockIdx.x & 15) * 64;
    __shared__ __align__(16) u16 P_lds[4][16][40];
    __shared__ float al_lds[4][16];
    __shared__ float lv_lds[4][16];
    __shared__ float O_lds[4][16][33];
    __shared__ float pw_s[32][32];
    __shared__ float pb_s[32];
    int t = threadIdx.x;
    int w = t >> 6, lane = t & 63;
    int q = lane >> 4, idx = lane & 15;

    for (int e = t; e < 1024; e += 256) pw_s[e >> 5][e & 31] = proj_w[e];
    if (t < 32) pb_s[t] = proj_b[t];
    __syncthreads();

    const u16* Qb = Qt + (size_t)b * NP * 32;
    const u16* Kb = Kt + (size_t)b * NP * 32;
    const u16* Vp = Vb + (size_t)b * 32 * NP;

    int nrow = n0 + w * 16 + idx;
    bf16x8 aq = *(const bf16x8*)&Qb[(size_t)nrow * 32 + q * 8];

    f32x4 O0 = {0.f, 0.f, 0.f, 0.f}, O1 = {0.f, 0.f, 0.f, 0.f};
    float m_run[4] = {-1e30f, -1e30f, -1e30f, -1e30f};
    float l_run[4] = {0.f, 0.f, 0.f, 0.f};

    for (int m0 = 0; m0 < NP; m0 += 32) {
        bf16x8 bk0 = *(const bf16x8*)&Kb[(size_t)(m0 + idx) * 32 + q * 8];
        bf16x8 bk1 = *(const bf16x8*)&Kb[(size_t)(m0 + 16 + idx) * 32 + q * 8];
        bf16x8 va0 = *(const bf16x8*)&Vp[(size_t)idx * NP + m0 + q * 8];
        bf16x8 va1 = *(const bf16x8*)&Vp[(size_t)(16 + idx) * NP + m0 + q * 8];
        f32x4 z = {0.f, 0.f, 0.f, 0.f};
        f32x4 S0 = __builtin_amdgcn_mfma_f32_16x16x32_bf16(aq, bk0, z, 0, 0, 0);
        f32x4 S1 = __builtin_amdgcn_mfma_f32_16x16x32_bf16(aq, bk1, z, 0, 0, 0);
        float mx[4], p0[4], p1[4], alpha[4];
#pragma unroll
        for (int r = 0; r < 4; ++r) mx[r] = fmaxf(S0[r], S1[r]);
#pragma unroll
        for (int off = 1; off < 16; off <<= 1)
#pragma unroll
            for (int r = 0; r < 4; ++r) mx[r] = fmaxf(mx[r], __shfl_xor(mx[r], off, 64));
#pragma unroll
        for (int r = 0; r < 4; ++r) {
            float nm = fmaxf(m_run[r], mx[r]);
            alpha[r] = __expf(m_run[r] - nm);
            m_run[r] = nm;
            p0[r] = __expf(S0[r] - nm);
            p1[r] = __expf(S1[r] - nm);
        }
#pragma unroll
        for (int r = 0; r < 4; ++r) {
            float s = p0[r] + p1[r];
#pragma unroll
            for (int off = 1; off < 16; off <<= 1) s += __shfl_xor(s, off, 64);
            l_run[r] = l_run[r] * alpha[r] + s;
        }
#pragma unroll
        for (int r = 0; r < 4; ++r) {
            P_lds[w][q * 4 + r][idx]      = f2bf(p0[r]);
            P_lds[w][q * 4 + r][idx + 16] = f2bf(p1[r]);
        }
        if (idx == 0) {
#pragma unroll
            for (int r = 0; r < 4; ++r) al_lds[w][q * 4 + r] = alpha[r];
        }
        float an = al_lds[w][idx];
#pragma unroll
        for (int r = 0; r < 4; ++r) { O0[r] *= an; O1[r] *= an; }
        bf16x8 pf = *(const bf16x8*)&P_lds[w][idx][q * 8];
        O0 = __builtin_amdgcn_mfma_f32_16x16x32_bf16(va0, pf, O0, 0, 0, 0);
        O1 = __builtin_amdgcn_mfma_f32_16x16x32_bf16(va1, pf, O1, 0, 0, 0);
    }
    if (idx == 0) {
#pragma unroll
        for (int r = 0; r < 4; ++r) lv_lds[w][q * 4 + r] = l_run[r];
    }
    float linv = 1.0f / lv_lds[w][idx];
#pragma unroll
    for (int r = 0; r < 4; ++r) {
        O_lds[w][idx][q * 4 + r]      = O0[r] * linv;
        O_lds[w][idx][q * 4 + r + 16] = O1[r] * linv;
    }
    float o0[4], o1[4];
#pragma unroll
    for (int r = 0; r < 4; ++r) { o0[r] = pb_s[q * 4 + r]; o1[r] = pb_s[q * 4 + r + 16]; }
#pragma unroll
    for (int c = 0; c < 32; ++c) {
        float xv = O_lds[w][idx][c];
#pragma unroll
        for (int r = 0; r < 4; ++r) {
            o0[r] += pw_s[q * 4 + r][c] * xv;
            o1[r] += pw_s[q * 4 + r + 16][c] * xv;
        }
    }
    u16* yrow = ygt + ((size_t)b * NP + nrow) * CC;
    ushort4 w0, w1;
    w0.x = f2bf(o0[0]); w0.y = f2bf(o0[1]); w0.z = f2bf(o0[2]); w0.w = f2bf(o0[3]);
    w1.x = f2bf(o1[0]); w1.y = f2bf(o1[1]); w1.z = f2bf(o1[2]); w1.w = f2bf(o1[3]);
    *(ushort4*)&yrow[q * 4] = w0;
    *(ushort4*)&yrow[q * 4 + 16] = w1;
}

// ---------------- fp32 -> bf16 weight convert ----------------
__global__ __launch_bounds__(256)
void convert_w_kernel(const float* __restrict__ w1, u16* __restrict__ d1,
                      const float* __restrict__ w2, u16* __restrict__ d2) {
    int blk = blockIdx.x;
    const float* src = (blk < 256) ? w1 : w2;
    u16* dst = (blk < 256) ? d1 : d2;
    int i = ((blk & 255) * 256 + threadIdx.x) * 4;
    float4 v = *(const float4*)(src + i);
    ushort4 o;
    o.x = f2bf(v.x); o.y = f2bf(v.y); o.z = f2bf(v.z); o.w = f2bf(v.w);
    *(ushort4*)(dst + i) = o;
}

// ---------------- bf16 MFMA GEMM, 128x128 tile, BK=64, XOR-swizzled LDS ----------------
template <int K, bool RELU, bool TRANS_OUT>
__global__ __launch_bounds__(256)
void mfma_gemm_kernel(const u16* __restrict__ A, const u16* __restrict__ Bt,
                      const float* __restrict__ bias, void* __restrict__ Yv, int M) {
    __shared__ __align__(16) u16 As[128][64];
    __shared__ __align__(16) u16 Bs[128][64];
    int mt = blockIdx.x, nt = blockIdx.y;
    const u16* Ab = A + (size_t)mt * 128 * K;
    const u16* Bb = Bt + (size_t)nt * 128 * K;
    int t = threadIdx.x;
    int w = t >> 6, lane = t & 63;
    int q = lane >> 4, idx = lane & 15;
    int wr = (w >> 1) * 64, wc = (w & 1) * 64;
    int srow = lane >> 3;
    int gch = (lane & 7) ^ srow;

    f32x4 acc[4][4];
#pragma unroll
    for (int i = 0; i < 4; ++i)
#pragma unroll
        for (int j = 0; j < 4; ++j) { f32x4 z = {0.f, 0.f, 0.f, 0.f}; acc[i][j] = z; }

    for (int k0 = 0; k0 < K; k0 += 64) {
        __syncthreads();
#pragma unroll
        for (int p = 0; p < 4; ++p) {
            int r = w * 32 + p * 8 + srow;
            __builtin_amdgcn_global_load_lds(
                (const __attribute__((address_space(1))) void*)(Ab + (size_t)r * K + k0 + gch * 8),
                (__attribute__((address_space(3))) void*)(&As[w * 32 + p * 8][0]),
                16, 0, 0);
        }
#pragma unroll
        for (int p = 0; p < 4; ++p) {
            int r = w * 32 + p * 8 + srow;
            __builtin_amdgcn_global_load_lds(
                (const __attribute__((address_space(1))) void*)(Bb + (size_t)r * K + k0 + gch * 8),
                (__attribute__((address_space(3))) void*)(&Bs[w * 32 + p * 8][0]),
                16, 0, 0);
        }
        __syncthreads();
#pragma unroll
        for (int h = 0; h < 2; ++h) {
            bf16x8 af[4], bfr[4];
#pragma unroll
            for (int i = 0; i < 4; ++i)
                af[i] = *(const bf16x8*)&As[wr + i * 16 + idx][(((q + 4 * h) ^ (idx & 7)) * 8)];
#pragma unroll
            for (int j = 0; j < 4; ++j)
                bfr[j] = *(const bf16x8*)&Bs[wc + j * 16 + idx][(((q + 4 * h) ^ (idx & 7)) * 8)];
#pragma unroll
            for (int i = 0; i < 4; ++i)
#pragma unroll
                for (int j = 0; j < 4; ++j)
                    acc[i][j] = __builtin_amdgcn_mfma_f32_16x16x32_bf16(af[i], bfr[j], acc[i][j], 0, 0, 0);
        }
    }

    if (TRANS_OUT) {
        u16* Y = (u16*)Yv;
#pragma unroll
        for (int i = 0; i < 4; ++i) {
            int m0 = mt * 128 + wr + i * 16 + q * 4;
            float b0 = bias[m0], b1 = bias[m0 + 1], b2 = bias[m0 + 2], b3 = bias[m0 + 3];
#pragma unroll
            for (int j = 0; j < 4; ++j) {
                int n = nt * 128 + wc + j * 16 + idx;
                f32x4 v = acc[i][j];
                float r0 = v.x + b0, r1 = v.y + b1, r2 = v.z + b2, r3 = v.w + b3;
                if (RELU) {
                    r0 = fmaxf(r0, 0.f); r1 = fmaxf(r1, 0.f);
                    r2 = fmaxf(r2, 0.f); r3 = fmaxf(r3, 0.f);
                }
                ushort4 o;
                o.x = f2bf(r0); o.y = f2bf(r1); o.z = f2bf(r2); o.w = f2bf(r3);
                *(ushort4*)&Y[(size_t)n * (size_t)M + m0] = o;
            }
        }
    } else {
        float* Y = (float*)Yv;
#pragma unroll
        for (int i = 0; i < 4; ++i) {
            int m0 = mt * 128 + wr + i * 16 + q * 4;
            float b0 = bias[m0], b1 = bias[m0 + 1], b2 = bias[m0 + 2], b3 = bias[m0 + 3];
#pragma unroll
            for (int j = 0; j < 4; ++j) {
                int ng = nt * 128 + wc + j * 16 + idx;
                int bb = ng >> 10, nn = ng & 1023;
                f32x4 v = acc[i][j];
                float* p = Y + ((size_t)bb * M + m0) * NP + nn;
                p[0]      = v.x + b0;
                p[NP]     = v.y + b1;
                p[2 * NP] = v.z + b2;
                p[3 * NP] = v.w + b3;
            }
        }
    }
}

extern "C" void kernel_launch(void* const* d_in, const int* in_sizes, int n_in,
                              void* d_out, int out_size, void* d_ws, size_t ws_size,
                              hipStream_t stream) {
    const float* x      = (const float*)d_in[0];
    const float* fc1_w  = (const float*)d_in[1];
    const float* fc1_b  = (const float*)d_in[2];
    const float* fc2_w  = (const float*)d_in[3];
    const float* fc2_b  = (const float*)d_in[4];
    const float* qkv_w  = (const float*)d_in[5];
    const float* qkv_b  = (const float*)d_in[6];
    const float* proj_w = (const float*)d_in[7];
    const float* proj_b = (const float*)d_in[8];
    const float* ffn1_w = (const float*)d_in[9];
    const float* ffn1_b = (const float*)d_in[10];
    const float* ffn2_w = (const float*)d_in[11];
    const float* ffn2_b = (const float*)d_in[12];
    float* out = (float*)d_out;

    // layout: [w1b 512K][w2b 512K][ygt 8M][ht 32M]; pre-FFN buffers overlap ht (dead by then)
    u16* w1b = (u16*)d_ws;
    u16* w2b = w1b + 262144;
    u16* ygt = w2b + 262144;                       // [b*1024][256] bf16
    u16* ht  = ygt + (size_t)BB * NP * CC;         // [b*1024][1024] bf16
    float* sig  = (float*)ht;                      // 16 KB
    float* s_mean = sig + BB * CC;                 // 16 KB
    float* yg32 = s_mean + BB * CC;                // 2 MB
    u16* Qt = (u16*)(yg32 + (size_t)BB * 32 * NP); // 1 MB
    u16* Kt = Qt + (size_t)BB * NP * 32;           // 1 MB
    u16* Vb = Kt + (size_t)BB * NP * 32;           // 1 MB

    se_mean_kernel<<<BB * CC, 256, 0, stream>>>(x, s_mean);
    convert_w_kernel<<<512, 256, 0, stream>>>(ffn1_w, w1b, ffn2_w, w2b);
    se_mlp_kernel<<<BB, 256, 0, stream>>>(s_mean, fc1_w, fc1_b, fc2_w, fc2_b, sig);
    scale_transpose_kernel<<<dim3(16, 4, BB), 256, 0, stream>>>(x, sig, yg32, ygt);
    qkv_kernel<<<dim3(16, BB), 256, 0, stream>>>(yg32, qkv_w, qkv_b, Qt, Kt, Vb);
    attn_mfma_kernel<<<BB * 16, 256, 0, stream>>>(Qt, Kt, Vb, proj_w, proj_b, ygt);

    // FFN1: ht[nflat][1024] bf16 (ReLU) = ffn1_w(1024x256) @ ygt
    mfma_gemm_kernel<256, true, true><<<dim3(8, 128), 256, 0, stream>>>(
        w1b, ygt, ffn1_b, (void*)ht, 1024);
    // FFN2: out[b][256][1024] fp32 = ffn2_w(256x1024) @ ht
    mfma_gemm_kernel<1024, false, false><<<dim3(2, 128), 256, 0, stream>>>(
        w2b, ht, ffn2_b, (void*)out, 256);
}

// Round 5
// 181.682 us; speedup vs baseline: 3.2604x; 1.0599x over previous
//
#include <hip/hip_runtime.h>
#include <cstdint>
#include <cstddef>

#define BB 16
#define CC 256
#define NP 1024   // H*W

typedef __attribute__((ext_vector_type(8))) short bf16x8;
typedef __attribute__((ext_vector_type(4))) float f32x4;
typedef unsigned short u16;

__device__ __forceinline__ u16 f2bf(float f) {
    union { float f; uint32_t u; } v; v.f = f;
    uint32_t u = v.u;
    return (u16)((u + 0x7FFFu + ((u >> 16) & 1u)) >> 16);   // RNE
}

// ---------------- SE mean: one block per (b,c) row ----------------
__global__ __launch_bounds__(256)
void se_mean_kernel(const float* __restrict__ x, float* __restrict__ s_mean) {
    int bc = blockIdx.x;
    const float* p = x + (size_t)bc * NP;
    int t = threadIdx.x;
    float4 v = *(const float4*)(p + t * 4);
    float s = (v.x + v.y) + (v.z + v.w);
#pragma unroll
    for (int off = 32; off; off >>= 1) s += __shfl_down(s, off, 64);
    __shared__ float red[4];
    if ((t & 63) == 0) red[t >> 6] = s;
    __syncthreads();
    if (t == 0) s_mean[bc] = (red[0] + red[1] + red[2] + red[3]) * (1.0f / NP);
}

// ---------------- SE mlp: fc1+relu -> fc2+sigmoid (tiny) ----------------
__global__ __launch_bounds__(256)
void se_mlp_kernel(const float* __restrict__ s_mean,
                   const float* __restrict__ fc1_w, const float* __restrict__ fc1_b,
                   const float* __restrict__ fc2_w, const float* __restrict__ fc2_b,
                   float* __restrict__ sig) {
    int b = blockIdx.x;
    __shared__ float sm[CC];
    __shared__ float h1[64];
    int t = threadIdx.x;
    sm[t] = s_mean[b * CC + t];
    __syncthreads();
    if (t < 64) {
        float a = fc1_b[t];
        for (int c = 0; c < CC; ++c) a += fc1_w[t * CC + c] * sm[c];
        h1[t] = fmaxf(a, 0.f);
    }
    __syncthreads();
    float a = fc2_b[t];
#pragma unroll 8
    for (int c = 0; c < 64; ++c) a += fc2_w[t * 64 + c] * h1[c];
    sig[b * CC + t] = 1.f / (1.f + __expf(-a));
}

// ---- scale + transpose (+ fused qkv on ct==0 blocks) ----
// ygt bf16 [b][n][c] for c>=32; Qt [b][n][32] (x0.25, zero-pad 16..31), Kt likewise, Vb [b][32][n]
__global__ __launch_bounds__(256)
void scale_transpose_qkv_kernel(const float* __restrict__ x, const float* __restrict__ sig,
                                const float* __restrict__ qW, const float* __restrict__ qB,
                                u16* __restrict__ ygt, u16* __restrict__ Qt,
                                u16* __restrict__ Kt, u16* __restrict__ Vb) {
    // grid: (16 nt, 4 ct, BB)
    int nt = blockIdx.x, ct = blockIdx.y, b = blockIdx.z;
    __shared__ float tile[64][65];
    __shared__ float ws[64 * 32];
    __shared__ float bs[64];
    __shared__ float vtile[32][64];
    int t = threadIdx.x;
    const float* Xb = x + ((size_t)b * CC + ct * 64) * NP + nt * 64;
    if (ct == 0) {
        for (int e = t; e < 2048; e += 256) ws[e] = qW[e];
        if (t < 64) bs[t] = qB[t];
    }
#pragma unroll
    for (int p = 0; p < 4; ++p) {
        int e = t + p * 256;
        int c = e >> 4, n4 = (e & 15) * 4;
        float4 v = *(const float4*)&Xb[(size_t)c * NP + n4];
        float sc = sig[b * CC + ct * 64 + c];
        v.x *= sc; v.y *= sc; v.z *= sc; v.w *= sc;
        tile[c][n4] = v.x; tile[c][n4 + 1] = v.y; tile[c][n4 + 2] = v.z; tile[c][n4 + 3] = v.w;
    }
    __syncthreads();
    u16* Yb = ygt + ((size_t)b * NP + nt * 64) * CC + ct * 64;
#pragma unroll
    for (int p = 0; p < 4; ++p) {
        int e = t + p * 256;
        int n = e >> 4, c4 = (e & 15) * 4;
        if (ct * 64 + c4 >= 32) {
            ushort4 o;
            o.x = f2bf(tile[c4][n]);     o.y = f2bf(tile[c4 + 1][n]);
            o.z = f2bf(tile[c4 + 2][n]); o.w = f2bf(tile[c4 + 3][n]);
            *(ushort4*)&Yb[(size_t)n * CC + c4] = o;
        }
    }
    if (ct == 0) {
        int nn = t & 63, g = t >> 6;   // g: oc-group of 16
        int n = nt * 64 + nn;
        float acc[16];
#pragma unroll
        for (int oc = 0; oc < 16; ++oc) {
            int o = g * 16 + oc;
            float a = bs[o];
#pragma unroll
            for (int c = 0; c < 32; ++c) a += ws[o * 32 + c] * tile[c][nn];
            acc[oc] = a;
        }
        if (g == 0) {
            u16* qr = Qt + ((size_t)b * NP + n) * 32;
            ushort4 z4; z4.x = 0; z4.y = 0; z4.z = 0; z4.w = 0;
#pragma unroll
            for (int j = 0; j < 16; j += 4) {
                ushort4 o4;
                o4.x = f2bf(acc[j] * 0.25f);     o4.y = f2bf(acc[j + 1] * 0.25f);
                o4.z = f2bf(acc[j + 2] * 0.25f); o4.w = f2bf(acc[j + 3] * 0.25f);
                *(ushort4*)&qr[j] = o4;
            }
            *(ushort4*)&qr[16] = z4; *(ushort4*)&qr[20] = z4;
            *(ushort4*)&qr[24] = z4; *(ushort4*)&qr[28] = z4;
        } else if (g == 1) {
            u16* kr = Kt + ((size_t)b * NP + n) * 32;
            ushort4 z4; z4.x = 0; z4.y = 0; z4.z = 0; z4.w = 0;
#pragma unroll
            for (int j = 0; j < 16; j += 4) {
                ushort4 k4;
                k4.x = f2bf(acc[j]);     k4.y = f2bf(acc[j + 1]);
                k4.z = f2bf(acc[j + 2]); k4.w = f2bf(acc[j + 3]);
                *(ushort4*)&kr[j] = k4;
            }
            *(ushort4*)&kr[16] = z4; *(ushort4*)&kr[20] = z4;
            *(ushort4*)&kr[24] = z4; *(ushort4*)&kr[28] = z4;
        } else {
#pragma unroll
            for (int oc = 0; oc < 16; ++oc) vtile[(g - 2) * 16 + oc][nn] = acc[oc];
        }
        __syncthreads();
        for (int e = t; e < 2048; e += 256) {
            int c = e >> 6, nn2 = e & 63;
            Vb[(size_t)b * 32 * NP + (size_t)c * NP + nt * 64 + nn2] = f2bf(vtile[c][nn2]);
        }
    }
}

// ---------------- MFMA flash attention + fused proj ----------------
// 512 threads: 8 waves = 4 row-groups x 2 key-halves; 2-way merge epilogue.
__global__ __launch_bounds__(512)
void attn_mfma_kernel(const u16* __restrict__ Qt, const u16* __restrict__ Kt,
                      const u16* __restrict__ Vb,
                      const float* __restrict__ proj_w, const float* __restrict__ proj_b,
                      u16* __restrict__ ygt) {
    int b = blockIdx.x >> 4;
    int n0 = (blockIdx.x & 15) * 64;
    __shared__ __align__(16) u16 P_lds[8][16][40];
    __shared__ float al_lds[8][16];
    __shared__ float sm_lds[8][16];
    __shared__ float sl_lds[8][16];
    __shared__ float O_lds[8][16][33];
    __shared__ float pw_s[32][32];
    __shared__ float pb_s[32];
    int t = threadIdx.x;
    int w = t >> 6, lane = t & 63;
    int q = lane >> 4, idx = lane & 15;
    int rg = w & 3, kh = w >> 2;

    for (int e = t; e < 1024; e += 512) pw_s[e >> 5][e & 31] = proj_w[e];
    if (t < 32) pb_s[t] = proj_b[t];
    __syncthreads();

    const u16* Qb = Qt + (size_t)b * NP * 32;
    const u16* Kb = Kt + (size_t)b * NP * 32;
    const u16* Vp = Vb + (size_t)b * 32 * NP;

    int nrow = n0 + rg * 16 + idx;
    bf16x8 aq = *(const bf16x8*)&Qb[(size_t)nrow * 32 + q * 8];

    f32x4 O0 = {0.f, 0.f, 0.f, 0.f}, O1 = {0.f, 0.f, 0.f, 0.f};
    float m_run[4] = {-1e30f, -1e30f, -1e30f, -1e30f};
    float l_run[4] = {0.f, 0.f, 0.f, 0.f};

    int mbase = kh * 512;
    for (int m0 = mbase; m0 < mbase + 512; m0 += 32) {
        bf16x8 bk0 = *(const bf16x8*)&Kb[(size_t)(m0 + idx) * 32 + q * 8];
        bf16x8 bk1 = *(const bf16x8*)&Kb[(size_t)(m0 + 16 + idx) * 32 + q * 8];
        bf16x8 va0 = *(const bf16x8*)&Vp[(size_t)idx * NP + m0 + q * 8];
        bf16x8 va1 = *(const bf16x8*)&Vp[(size_t)(16 + idx) * NP + m0 + q * 8];
        f32x4 z = {0.f, 0.f, 0.f, 0.f};
        f32x4 S0 = __builtin_amdgcn_mfma_f32_16x16x32_bf16(aq, bk0, z, 0, 0, 0);
        f32x4 S1 = __builtin_amdgcn_mfma_f32_16x16x32_bf16(aq, bk1, z, 0, 0, 0);
        float mx[4], p0[4], p1[4], alpha[4];
#pragma unroll
        for (int r = 0; r < 4; ++r) mx[r] = fmaxf(S0[r], S1[r]);
#pragma unroll
        for (int off = 1; off < 16; off <<= 1)
#pragma unroll
            for (int r = 0; r < 4; ++r) mx[r] = fmaxf(mx[r], __shfl_xor(mx[r], off, 64));
#pragma unroll
        for (int r = 0; r < 4; ++r) {
            float nm = fmaxf(m_run[r], mx[r]);
            alpha[r] = __expf(m_run[r] - nm);
            m_run[r] = nm;
            p0[r] = __expf(S0[r] - nm);
            p1[r] = __expf(S1[r] - nm);
        }
#pragma unroll
        for (int r = 0; r < 4; ++r) {
            float s = p0[r] + p1[r];
#pragma unroll
            for (int off = 1; off < 16; off <<= 1) s += __shfl_xor(s, off, 64);
            l_run[r] = l_run[r] * alpha[r] + s;
        }
#pragma unroll
        for (int r = 0; r < 4; ++r) {
            P_lds[w][q * 4 + r][idx]      = f2bf(p0[r]);
            P_lds[w][q * 4 + r][idx + 16] = f2bf(p1[r]);
        }
        if (idx == 0) {
#pragma unroll
            for (int r = 0; r < 4; ++r) al_lds[w][q * 4 + r] = alpha[r];
        }
        float an = al_lds[w][idx];
#pragma unroll
        for (int r = 0; r < 4; ++r) { O0[r] *= an; O1[r] *= an; }
        bf16x8 pf = *(const bf16x8*)&P_lds[w][idx][q * 8];
        O0 = __builtin_amdgcn_mfma_f32_16x16x32_bf16(va0, pf, O0, 0, 0, 0);
        O1 = __builtin_amdgcn_mfma_f32_16x16x32_bf16(va1, pf, O1, 0, 0, 0);
    }
    if (idx == 0) {
#pragma unroll
        for (int r = 0; r < 4; ++r) {
            sm_lds[w][q * 4 + r] = m_run[r];
            sl_lds[w][q * 4 + r] = l_run[r];
        }
    }
#pragma unroll
    for (int r = 0; r < 4; ++r) {
        O_lds[w][idx][q * 4 + r]      = O0[r];
        O_lds[w][idx][q * 4 + r + 16] = O1[r];
    }
    __syncthreads();
    if (w < 4) {
        // merge key-halves for row idx of row-group w
        float ma = sm_lds[w][idx], mb = sm_lds[w + 4][idx];
        float la = sl_lds[w][idx], lb = sl_lds[w + 4][idx];
        float gm = fmaxf(ma, mb);
        float ea = __expf(ma - gm), eb = __expf(mb - gm);
        float linv = 1.f / (la * ea + lb * eb);
#pragma unroll
        for (int r = 0; r < 4; ++r) {
            int c0 = q * 4 + r;
            O_lds[w][idx][c0]      = (O_lds[w][idx][c0] * ea + O_lds[w + 4][idx][c0] * eb) * linv;
            O_lds[w][idx][c0 + 16] = (O_lds[w][idx][c0 + 16] * ea + O_lds[w + 4][idx][c0 + 16] * eb) * linv;
        }
        // fused proj (reads all 32 c of row idx — written by this wave's 16 idx-lanes)
        float o0[4], o1[4];
#pragma unroll
        for (int r = 0; r < 4; ++r) { o0[r] = pb_s[q * 4 + r]; o1[r] = pb_s[q * 4 + r + 16]; }
#pragma unroll
        for (int c = 0; c < 32; ++c) {
            float xv = O_lds[w][idx][c];
#pragma unroll
            for (int r = 0; r < 4; ++r) {
                o0[r] += pw_s[q * 4 + r][c] * xv;
                o1[r] += pw_s[q * 4 + r + 16][c] * xv;
            }
        }
        u16* yrow = ygt + ((size_t)b * NP + n0 + w * 16 + idx) * CC;
        ushort4 w0, w1;
        w0.x = f2bf(o0[0]); w0.y = f2bf(o0[1]); w0.z = f2bf(o0[2]); w0.w = f2bf(o0[3]);
        w1.x = f2bf(o1[0]); w1.y = f2bf(o1[1]); w1.z = f2bf(o1[2]); w1.w = f2bf(o1[3]);
        *(ushort4*)&yrow[q * 4] = w0;
        *(ushort4*)&yrow[q * 4 + 16] = w1;
    }
}

// ---------------- fp32 -> bf16 weight convert ----------------
__global__ __launch_bounds__(256)
void convert_w_kernel(const float* __restrict__ w1, u16* __restrict__ d1,
                      const float* __restrict__ w2, u16* __restrict__ d2) {
    int blk = blockIdx.x;
    const float* src = (blk < 256) ? w1 : w2;
    u16* dst = (blk < 256) ? d1 : d2;
    int i = ((blk & 255) * 256 + threadIdx.x) * 4;
    float4 v = *(const float4*)(src + i);
    ushort4 o;
    o.x = f2bf(v.x); o.y = f2bf(v.y); o.z = f2bf(v.z); o.w = f2bf(v.w);
    *(ushort4*)(dst + i) = o;
}

// ---------------- bf16 MFMA GEMM, 128x128 tile, BK=64, double-buffered LDS ----------------
// One barrier per K-iter; next-buffer loads issued right after the barrier, before
// compute on the current buffer, so the following barrier's vmcnt drain is hidden.
template <int K, bool RELU, bool TRANS_OUT>
__global__ __launch_bounds__(256)
void mfma_gemm_kernel(const u16* __restrict__ A, const u16* __restrict__ Bt,
                      const float* __restrict__ bias, void* __restrict__ Yv, int M) {
    __shared__ __align__(16) u16 As[2][128][64];
    __shared__ __align__(16) u16 Bs[2][128][64];
    constexpr int NIT = K / 64;
    int mt = blockIdx.x, nt = blockIdx.y;
    const u16* Ab = A + (size_t)mt * 128 * K;
    const u16* Bb = Bt + (size_t)nt * 128 * K;
    int t = threadIdx.x;
    int w = t >> 6, lane = t & 63;
    int q = lane >> 4, idx = lane & 15;
    int wr = (w >> 1) * 64, wc = (w & 1) * 64;
    int srow = lane >> 3;
    int gch = (lane & 7) ^ srow;

    f32x4 acc[4][4];
#pragma unroll
    for (int i = 0; i < 4; ++i)
#pragma unroll
        for (int j = 0; j < 4; ++j) { f32x4 z = {0.f, 0.f, 0.f, 0.f}; acc[i][j] = z; }

#define ISSUE_LOADS(buf, k0)                                                              \
    {                                                                                     \
        _Pragma("unroll")                                                                 \
        for (int p = 0; p < 4; ++p) {                                                     \
            int r = w * 32 + p * 8 + srow;                                                \
            __builtin_amdgcn_global_load_lds(                                             \
                (const __attribute__((address_space(1))) void*)(Ab + (size_t)r * K + (k0) + gch * 8), \
                (__attribute__((address_space(3))) void*)(&As[buf][w * 32 + p * 8][0]),   \
                16, 0, 0);                                                                \
        }                                                                                 \
        _Pragma("unroll")                                                                 \
        for (int p = 0; p < 4; ++p) {                                                     \
            int r = w * 32 + p * 8 + srow;                                                \
            __builtin_amdgcn_global_load_lds(                                             \
                (const __attribute__((address_space(1))) void*)(Bb + (size_t)r * K + (k0) + gch * 8), \
                (__attribute__((address_space(3))) void*)(&Bs[buf][w * 32 + p * 8][0]),   \
                16, 0, 0);                                                                \
        }                                                                                 \
    }

    ISSUE_LOADS(0, 0)
    for (int ki = 0; ki < NIT; ++ki) {
        int cur = ki & 1;
        __syncthreads();                       // buf[cur] ready; prior reads of buf[cur^1] done
        if (ki + 1 < NIT) ISSUE_LOADS(cur ^ 1, (ki + 1) * 64)
#pragma unroll
        for (int h = 0; h < 2; ++h) {
            bf16x8 af[4], bfr[4];
#pragma unroll
            for (int i = 0; i < 4; ++i)
                af[i] = *(const bf16x8*)&As[cur][wr + i * 16 + idx][(((q + 4 * h) ^ (idx & 7)) * 8)];
#pragma unroll
            for (int j = 0; j < 4; ++j)
                bfr[j] = *(const bf16x8*)&Bs[cur][wc + j * 16 + idx][(((q + 4 * h) ^ (idx & 7)) * 8)];
#pragma unroll
            for (int i = 0; i < 4; ++i)
#pragma unroll
                for (int j = 0; j < 4; ++j)
                    acc[i][j] = __builtin_amdgcn_mfma_f32_16x16x32_bf16(af[i], bfr[j], acc[i][j], 0, 0, 0);
        }
    }
#undef ISSUE_LOADS

    if (TRANS_OUT) {
        u16* Y = (u16*)Yv;
#pragma unroll
        for (int i = 0; i < 4; ++i) {
            int m0 = mt * 128 + wr + i * 16 + q * 4;
            float b0 = bias[m0], b1 = bias[m0 + 1], b2 = bias[m0 + 2], b3 = bias[m0 + 3];
#pragma unroll
            for (int j = 0; j < 4; ++j) {
                int n = nt * 128 + wc + j * 16 + idx;
                f32x4 v = acc[i][j];
                float r0 = v.x + b0, r1 = v.y + b1, r2 = v.z + b2, r3 = v.w + b3;
                if (RELU) {
                    r0 = fmaxf(r0, 0.f); r1 = fmaxf(r1, 0.f);
                    r2 = fmaxf(r2, 0.f); r3 = fmaxf(r3, 0.f);
                }
                ushort4 o;
                o.x = f2bf(r0); o.y = f2bf(r1); o.z = f2bf(r2); o.w = f2bf(r3);
                *(ushort4*)&Y[(size_t)n * (size_t)M + m0] = o;
            }
        }
    } else {
        float* Y = (float*)Yv;
#pragma unroll
        for (int i = 0; i < 4; ++i) {
            int m0 = mt * 128 + wr + i * 16 + q * 4;
            float b0 = bias[m0], b1 = bias[m0 + 1], b2 = bias[m0 + 2], b3 = bias[m0 + 3];
#pragma unroll
            for (int j = 0; j < 4; ++j) {
                int ng = nt * 128 + wc + j * 16 + idx;
                int bb = ng >> 10, nn = ng & 1023;
                f32x4 v = acc[i][j];
                float* p = Y + ((size_t)bb * M + m0) * NP + nn;
                p[0]      = v.x + b0;
                p[NP]     = v.y + b1;
                p[2 * NP] = v.z + b2;
                p[3 * NP] = v.w + b3;
            }
        }
    }
}

extern "C" void kernel_launch(void* const* d_in, const int* in_sizes, int n_in,
                              void* d_out, int out_size, void* d_ws, size_t ws_size,
                              hipStream_t stream) {
    const float* x      = (const float*)d_in[0];
    const float* fc1_w  = (const float*)d_in[1];
    const float* fc1_b  = (const float*)d_in[2];
    const float* fc2_w  = (const float*)d_in[3];
    const float* fc2_b  = (const float*)d_in[4];
    const float* qkv_w  = (const float*)d_in[5];
    const float* qkv_b  = (const float*)d_in[6];
    const float* proj_w = (const float*)d_in[7];
    const float* proj_b = (const float*)d_in[8];
    const float* ffn1_w = (const float*)d_in[9];
    const float* ffn1_b = (const float*)d_in[10];
    const float* ffn2_w = (const float*)d_in[11];
    const float* ffn2_b = (const float*)d_in[12];
    float* out = (float*)d_out;

    // layout: [w1b 512K][w2b 512K][ygt 8M][ht 32M]; pre-FFN buffers overlap ht (dead by FFN1)
    u16* w1b = (u16*)d_ws;
    u16* w2b = w1b + 262144;
    u16* ygt = w2b + 262144;                         // [b*1024][256] bf16
    u16* ht  = ygt + (size_t)BB * NP * CC;           // [b*1024][1024] bf16
    float* sig    = (float*)ht;                      // 16 KB
    float* s_mean = sig + BB * CC;                   // 16 KB
    u16* Qt = (u16*)(s_mean + BB * CC);              // 1 MB
    u16* Kt = Qt + (size_t)BB * NP * 32;             // 1 MB
    u16* Vb = Kt + (size_t)BB * NP * 32;             // 1 MB

    se_mean_kernel<<<BB * CC, 256, 0, stream>>>(x, s_mean);
    convert_w_kernel<<<512, 256, 0, stream>>>(ffn1_w, w1b, ffn2_w, w2b);
    se_mlp_kernel<<<BB, 256, 0, stream>>>(s_mean, fc1_w, fc1_b, fc2_w, fc2_b, sig);
    scale_transpose_qkv_kernel<<<dim3(16, 4, BB), 256, 0, stream>>>(
        x, sig, qkv_w, qkv_b, ygt, Qt, Kt, Vb);
    attn_mfma_kernel<<<BB * 16, 512, 0, stream>>>(Qt, Kt, Vb, proj_w, proj_b, ygt);

    // FFN1: ht[nflat][1024] bf16 (ReLU) = ffn1_w(1024x256) @ ygt
    mfma_gemm_kernel<256, true, true><<<dim3(8, 128), 256, 0, stream>>>(
        w1b, ygt, ffn1_b, (void*)ht, 1024);
    // FFN2: out[b][256][1024] fp32 = ffn2_w(256x1024) @ ht
    mfma_gemm_kernel<1024, false, false><<<dim3(2, 128), 256, 0, stream>>>(
        w2b, ht, ffn2_b, (void*)out, 256);
}

// Round 6
// 180.062 us; speedup vs baseline: 3.2897x; 1.0090x over previous
//
#include <hip/hip_runtime.h>
#include <cstdint>
#include <cstddef>

#define BB 16
#define CC 256
#define NP 1024   // H*W

typedef __attribute__((ext_vector_type(8))) short bf16x8;
typedef __attribute__((ext_vector_type(4))) float f32x4;
typedef unsigned short u16;

__device__ __forceinline__ u16 f2bf(float f) {
    union { float f; uint32_t u; } v; v.f = f;
    uint32_t u = v.u;
    return (u16)((u + 0x7FFFu + ((u >> 16) & 1u)) >> 16);   // RNE
}

// ---------------- SE mean (blocks 0..4095) + weight convert (blocks 4096..4607) ----------------
__global__ __launch_bounds__(256)
void se_mean_conv_kernel(const float* __restrict__ x, float* __restrict__ s_mean,
                         const float* __restrict__ w1, u16* __restrict__ d1,
                         const float* __restrict__ w2, u16* __restrict__ d2) {
    int blk = blockIdx.x;
    int t = threadIdx.x;
    if (blk < BB * CC) {
        const float* p = x + (size_t)blk * NP;
        float4 v = *(const float4*)(p + t * 4);
        float s = (v.x + v.y) + (v.z + v.w);
#pragma unroll
        for (int off = 32; off; off >>= 1) s += __shfl_down(s, off, 64);
        __shared__ float red[4];
        if ((t & 63) == 0) red[t >> 6] = s;
        __syncthreads();
        if (t == 0) s_mean[blk] = (red[0] + red[1] + red[2] + red[3]) * (1.0f / NP);
    } else {
        int blk2 = blk - BB * CC;
        const float* src = (blk2 < 256) ? w1 : w2;
        u16* dst = (blk2 < 256) ? d1 : d2;
        int i = ((blk2 & 255) * 256 + t) * 4;
        float4 v = *(const float4*)(src + i);
        ushort4 o;
        o.x = f2bf(v.x); o.y = f2bf(v.y); o.z = f2bf(v.z); o.w = f2bf(v.w);
        *(ushort4*)(dst + i) = o;
    }
}

// ---------------- SE mlp: fc1+relu -> fc2+sigmoid (tiny) ----------------
__global__ __launch_bounds__(256)
void se_mlp_kernel(const float* __restrict__ s_mean,
                   const float* __restrict__ fc1_w, const float* __restrict__ fc1_b,
                   const float* __restrict__ fc2_w, const float* __restrict__ fc2_b,
                   float* __restrict__ sig) {
    int b = blockIdx.x;
    __shared__ float sm[CC];
    __shared__ float h1[64];
    int t = threadIdx.x;
    sm[t] = s_mean[b * CC + t];
    __syncthreads();
    if (t < 64) {
        float a = fc1_b[t];
        for (int c = 0; c < CC; ++c) a += fc1_w[t * CC + c] * sm[c];
        h1[t] = fmaxf(a, 0.f);
    }
    __syncthreads();
    float a = fc2_b[t];
#pragma unroll 8
    for (int c = 0; c < 64; ++c) a += fc2_w[t * 64 + c] * h1[c];
    sig[b * CC + t] = 1.f / (1.f + __expf(-a));
}

// ---- scale + transpose (+ fused qkv on ct==0 blocks) ----
__global__ __launch_bounds__(256)
void scale_transpose_qkv_kernel(const float* __restrict__ x, const float* __restrict__ sig,
                                const float* __restrict__ qW, const float* __restrict__ qB,
                                u16* __restrict__ ygt, u16* __restrict__ Qt,
                                u16* __restrict__ Kt, u16* __restrict__ Vb) {
    // grid: (16 nt, 4 ct, BB)
    int nt = blockIdx.x, ct = blockIdx.y, b = blockIdx.z;
    __shared__ float tile[64][65];
    __shared__ float ws[64 * 32];
    __shared__ float bs[64];
    __shared__ float vtile[32][64];
    int t = threadIdx.x;
    const float* Xb = x + ((size_t)b * CC + ct * 64) * NP + nt * 64;
    if (ct == 0) {
        for (int e = t; e < 2048; e += 256) ws[e] = qW[e];
        if (t < 64) bs[t] = qB[t];
    }
#pragma unroll
    for (int p = 0; p < 4; ++p) {
        int e = t + p * 256;
        int c = e >> 4, n4 = (e & 15) * 4;
        float4 v = *(const float4*)&Xb[(size_t)c * NP + n4];
        float sc = sig[b * CC + ct * 64 + c];
        v.x *= sc; v.y *= sc; v.z *= sc; v.w *= sc;
        tile[c][n4] = v.x; tile[c][n4 + 1] = v.y; tile[c][n4 + 2] = v.z; tile[c][n4 + 3] = v.w;
    }
    __syncthreads();
    u16* Yb = ygt + ((size_t)b * NP + nt * 64) * CC + ct * 64;
#pragma unroll
    for (int p = 0; p < 4; ++p) {
        int e = t + p * 256;
        int n = e >> 4, c4 = (e & 15) * 4;
        if (ct * 64 + c4 >= 32) {
            ushort4 o;
            o.x = f2bf(tile[c4][n]);     o.y = f2bf(tile[c4 + 1][n]);
            o.z = f2bf(tile[c4 + 2][n]); o.w = f2bf(tile[c4 + 3][n]);
            *(ushort4*)&Yb[(size_t)n * CC + c4] = o;
        }
    }
    if (ct == 0) {
        int nn = t & 63, g = t >> 6;
        int n = nt * 64 + nn;
        float acc[16];
#pragma unroll
        for (int oc = 0; oc < 16; ++oc) {
            int o = g * 16 + oc;
            float a = bs[o];
#pragma unroll
            for (int c = 0; c < 32; ++c) a += ws[o * 32 + c] * tile[c][nn];
            acc[oc] = a;
        }
        if (g == 0) {
            u16* qr = Qt + ((size_t)b * NP + n) * 32;
            ushort4 z4; z4.x = 0; z4.y = 0; z4.z = 0; z4.w = 0;
#pragma unroll
            for (int j = 0; j < 16; j += 4) {
                ushort4 o4;
                o4.x = f2bf(acc[j] * 0.25f);     o4.y = f2bf(acc[j + 1] * 0.25f);
                o4.z = f2bf(acc[j + 2] * 0.25f); o4.w = f2bf(acc[j + 3] * 0.25f);
                *(ushort4*)&qr[j] = o4;
            }
            *(ushort4*)&qr[16] = z4; *(ushort4*)&qr[20] = z4;
            *(ushort4*)&qr[24] = z4; *(ushort4*)&qr[28] = z4;
        } else if (g == 1) {
            u16* kr = Kt + ((size_t)b * NP + n) * 32;
            ushort4 z4; z4.x = 0; z4.y = 0; z4.z = 0; z4.w = 0;
#pragma unroll
            for (int j = 0; j < 16; j += 4) {
                ushort4 k4;
                k4.x = f2bf(acc[j]);     k4.y = f2bf(acc[j + 1]);
                k4.z = f2bf(acc[j + 2]); k4.w = f2bf(acc[j + 3]);
                *(ushort4*)&kr[j] = k4;
            }
            *(ushort4*)&kr[16] = z4; *(ushort4*)&kr[20] = z4;
            *(ushort4*)&kr[24] = z4; *(ushort4*)&kr[28] = z4;
        } else {
#pragma unroll
            for (int oc = 0; oc < 16; ++oc) vtile[(g - 2) * 16 + oc][nn] = acc[oc];
        }
        __syncthreads();
        for (int e = t; e < 2048; e += 256) {
            int c = e >> 6, nn2 = e & 63;
            Vb[(size_t)b * 32 * NP + (size_t)c * NP + nt * 64 + nn2] = f2bf(vtile[c][nn2]);
        }
    }
}

// ---------------- MFMA flash attention + fused proj ----------------
// 16 q-rows/block, 4 waves = 4-way key split (256 keys each, 8 serial iters);
// 4-way merge + proj on wave 0.
__global__ __launch_bounds__(256)
void attn_mfma_kernel(const u16* __restrict__ Qt, const u16* __restrict__ Kt,
                      const u16* __restrict__ Vb,
                      const float* __restrict__ proj_w, const float* __restrict__ proj_b,
                      u16* __restrict__ ygt) {
    int b = blockIdx.x >> 6;
    int n0 = (blockIdx.x & 63) * 16;
    __shared__ __align__(16) u16 P_lds[4][16][40];
    __shared__ float al_lds[4][16];
    __shared__ float sm_lds[4][16];
    __shared__ float sl_lds[4][16];
    __shared__ float O_lds[4][16][33];
    __shared__ float pw_s[32][32];
    __shared__ float pb_s[32];
    int t = threadIdx.x;
    int w = t >> 6, lane = t & 63;
    int q = lane >> 4, idx = lane & 15;

    for (int e = t; e < 1024; e += 256) pw_s[e >> 5][e & 31] = proj_w[e];
    if (t < 32) pb_s[t] = proj_b[t];
    __syncthreads();

    const u16* Qb = Qt + (size_t)b * NP * 32;
    const u16* Kb = Kt + (size_t)b * NP * 32;
    const u16* Vp = Vb + (size_t)b * 32 * NP;

    int nrow = n0 + idx;
    bf16x8 aq = *(const bf16x8*)&Qb[(size_t)nrow * 32 + q * 8];

    f32x4 O0 = {0.f, 0.f, 0.f, 0.f}, O1 = {0.f, 0.f, 0.f, 0.f};
    float m_run[4] = {-1e30f, -1e30f, -1e30f, -1e30f};
    float l_run[4] = {0.f, 0.f, 0.f, 0.f};

    int mbase = w * 256;
    for (int m0 = mbase; m0 < mbase + 256; m0 += 32) {
        bf16x8 bk0 = *(const bf16x8*)&Kb[(size_t)(m0 + idx) * 32 + q * 8];
        bf16x8 bk1 = *(const bf16x8*)&Kb[(size_t)(m0 + 16 + idx) * 32 + q * 8];
        bf16x8 va0 = *(const bf16x8*)&Vp[(size_t)idx * NP + m0 + q * 8];
        bf16x8 va1 = *(const bf16x8*)&Vp[(size_t)(16 + idx) * NP + m0 + q * 8];
        f32x4 z = {0.f, 0.f, 0.f, 0.f};
        f32x4 S0 = __builtin_amdgcn_mfma_f32_16x16x32_bf16(aq, bk0, z, 0, 0, 0);
        f32x4 S1 = __builtin_amdgcn_mfma_f32_16x16x32_bf16(aq, bk1, z, 0, 0, 0);
        float mx[4], p0[4], p1[4], alpha[4];
#pragma unroll
        for (int r = 0; r < 4; ++r) mx[r] = fmaxf(S0[r], S1[r]);
#pragma unroll
        for (int off = 1; off < 16; off <<= 1)
#pragma unroll
            for (int r = 0; r < 4; ++r) mx[r] = fmaxf(mx[r], __shfl_xor(mx[r], off, 64));
#pragma unroll
        for (int r = 0; r < 4; ++r) {
            float nm = fmaxf(m_run[r], mx[r]);
            alpha[r] = __expf(m_run[r] - nm);
            m_run[r] = nm;
            p0[r] = __expf(S0[r] - nm);
            p1[r] = __expf(S1[r] - nm);
        }
#pragma unroll
        for (int r = 0; r < 4; ++r) {
            float s = p0[r] + p1[r];
#pragma unroll
            for (int off = 1; off < 16; off <<= 1) s += __shfl_xor(s, off, 64);
            l_run[r] = l_run[r] * alpha[r] + s;
        }
#pragma unroll
        for (int r = 0; r < 4; ++r) {
            P_lds[w][q * 4 + r][idx]      = f2bf(p0[r]);
            P_lds[w][q * 4 + r][idx + 16] = f2bf(p1[r]);
        }
        if (idx == 0) {
#pragma unroll
            for (int r = 0; r < 4; ++r) al_lds[w][q * 4 + r] = alpha[r];
        }
        float an = al_lds[w][idx];
#pragma unroll
        for (int r = 0; r < 4; ++r) { O0[r] *= an; O1[r] *= an; }
        bf16x8 pf = *(const bf16x8*)&P_lds[w][idx][q * 8];
        O0 = __builtin_amdgcn_mfma_f32_16x16x32_bf16(va0, pf, O0, 0, 0, 0);
        O1 = __builtin_amdgcn_mfma_f32_16x16x32_bf16(va1, pf, O1, 0, 0, 0);
    }
    if (idx == 0) {
#pragma unroll
        for (int r = 0; r < 4; ++r) {
            sm_lds[w][q * 4 + r] = m_run[r];
            sl_lds[w][q * 4 + r] = l_run[r];
        }
    }
#pragma unroll
    for (int r = 0; r < 4; ++r) {
        O_lds[w][idx][q * 4 + r]      = O0[r];
        O_lds[w][idx][q * 4 + r + 16] = O1[r];
    }
    __syncthreads();
    if (w == 0) {
        // 4-way merge for row idx
        float m0_ = sm_lds[0][idx], m1 = sm_lds[1][idx], m2 = sm_lds[2][idx], m3 = sm_lds[3][idx];
        float gm = fmaxf(fmaxf(m0_, m1), fmaxf(m2, m3));
        float e0 = __expf(m0_ - gm), e1 = __expf(m1 - gm);
        float e2 = __expf(m2 - gm), e3 = __expf(m3 - gm);
        float linv = 1.f / (sl_lds[0][idx] * e0 + sl_lds[1][idx] * e1 +
                            sl_lds[2][idx] * e2 + sl_lds[3][idx] * e3);
#pragma unroll
        for (int r = 0; r < 4; ++r) {
            int c0 = q * 4 + r;
            O_lds[0][idx][c0] = (O_lds[0][idx][c0] * e0 + O_lds[1][idx][c0] * e1 +
                                 O_lds[2][idx][c0] * e2 + O_lds[3][idx][c0] * e3) * linv;
            int c1 = c0 + 16;
            O_lds[0][idx][c1] = (O_lds[0][idx][c1] * e0 + O_lds[1][idx][c1] * e1 +
                                 O_lds[2][idx][c1] * e2 + O_lds[3][idx][c1] * e3) * linv;
        }
        // fused proj for row idx (intra-wave LDS, no barrier needed)
        float o0[4], o1[4];
#pragma unroll
        for (int r = 0; r < 4; ++r) { o0[r] = pb_s[q * 4 + r]; o1[r] = pb_s[q * 4 + r + 16]; }
#pragma unroll
        for (int c = 0; c < 32; ++c) {
            float xv = O_lds[0][idx][c];
#pragma unroll
            for (int r = 0; r < 4; ++r) {
                o0[r] += pw_s[q * 4 + r][c] * xv;
                o1[r] += pw_s[q * 4 + r + 16][c] * xv;
            }
        }
        u16* yrow = ygt + ((size_t)b * NP + n0 + idx) * CC;
        ushort4 w0, w1;
        w0.x = f2bf(o0[0]); w0.y = f2bf(o0[1]); w0.z = f2bf(o0[2]); w0.w = f2bf(o0[3]);
        w1.x = f2bf(o1[0]); w1.y = f2bf(o1[1]); w1.z = f2bf(o1[2]); w1.w = f2bf(o1[3]);
        *(ushort4*)&yrow[q * 4] = w0;
        *(ushort4*)&yrow[q * 4 + 16] = w1;
    }
}

// ---------------- bf16 MFMA GEMM, 128x128 tile, BK=64, double-buffered ----------------
template <int K, bool RELU>
__global__ __launch_bounds__(256)
void mfma_gemm_kernel(const u16* __restrict__ A, const u16* __restrict__ Bt,
                      const float* __restrict__ bias, u16* __restrict__ Y, int M) {
    __shared__ __align__(16) u16 As[2][128][64];
    __shared__ __align__(16) u16 Bs[2][128][64];
    constexpr int NIT = K / 64;
    int mt = blockIdx.x, nt = blockIdx.y;
    const u16* Ab = A + (size_t)mt * 128 * K;
    const u16* Bb = Bt + (size_t)nt * 128 * K;
    int t = threadIdx.x;
    int w = t >> 6, lane = t & 63;
    int q = lane >> 4, idx = lane & 15;
    int wr = (w >> 1) * 64, wc = (w & 1) * 64;
    int srow = lane >> 3;
    int gch = (lane & 7) ^ srow;

    f32x4 acc[4][4];
#pragma unroll
    for (int i = 0; i < 4; ++i)
#pragma unroll
        for (int j = 0; j < 4; ++j) { f32x4 z = {0.f, 0.f, 0.f, 0.f}; acc[i][j] = z; }

#define ISSUE_LOADS(buf, k0)                                                              \
    {                                                                                     \
        _Pragma("unroll")                                                                 \
        for (int p = 0; p < 4; ++p) {                                                     \
            int r = w * 32 + p * 8 + srow;                                                \
            __builtin_amdgcn_global_load_lds(                                             \
                (const __attribute__((address_space(1))) void*)(Ab + (size_t)r * K + (k0) + gch * 8), \
                (__attribute__((address_space(3))) void*)(&As[buf][w * 32 + p * 8][0]),   \
                16, 0, 0);                                                                \
        }                                                                                 \
        _Pragma("unroll")                                                                 \
        for (int p = 0; p < 4; ++p) {                                                     \
            int r = w * 32 + p * 8 + srow;                                                \
            __builtin_amdgcn_global_load_lds(                                             \
                (const __attribute__((address_space(1))) void*)(Bb + (size_t)r * K + (k0) + gch * 8), \
                (__attribute__((address_space(3))) void*)(&Bs[buf][w * 32 + p * 8][0]),   \
                16, 0, 0);                                                                \
        }                                                                                 \
    }

    ISSUE_LOADS(0, 0)
    for (int ki = 0; ki < NIT; ++ki) {
        int cur = ki & 1;
        __syncthreads();
        if (ki + 1 < NIT) ISSUE_LOADS(cur ^ 1, (ki + 1) * 64)
#pragma unroll
        for (int h = 0; h < 2; ++h) {
            bf16x8 af[4], bfr[4];
#pragma unroll
            for (int i = 0; i < 4; ++i)
                af[i] = *(const bf16x8*)&As[cur][wr + i * 16 + idx][(((q + 4 * h) ^ (idx & 7)) * 8)];
#pragma unroll
            for (int j = 0; j < 4; ++j)
                bfr[j] = *(const bf16x8*)&Bs[cur][wc + j * 16 + idx][(((q + 4 * h) ^ (idx & 7)) * 8)];
#pragma unroll
            for (int i = 0; i < 4; ++i)
#pragma unroll
                for (int j = 0; j < 4; ++j)
                    acc[i][j] = __builtin_amdgcn_mfma_f32_16x16x32_bf16(af[i], bfr[j], acc[i][j], 0, 0, 0);
        }
    }
#undef ISSUE_LOADS

    // bf16 transposed output Y[n][m] with bias(+ReLU)
#pragma unroll
    for (int i = 0; i < 4; ++i) {
        int m0 = mt * 128 + wr + i * 16 + q * 4;
        float b0 = bias[m0], b1 = bias[m0 + 1], b2 = bias[m0 + 2], b3 = bias[m0 + 3];
#pragma unroll
        for (int j = 0; j < 4; ++j) {
            int n = nt * 128 + wc + j * 16 + idx;
            f32x4 v = acc[i][j];
            float r0 = v.x + b0, r1 = v.y + b1, r2 = v.z + b2, r3 = v.w + b3;
            if (RELU) {
                r0 = fmaxf(r0, 0.f); r1 = fmaxf(r1, 0.f);
                r2 = fmaxf(r2, 0.f); r3 = fmaxf(r3, 0.f);
            }
            ushort4 o;
            o.x = f2bf(r0); o.y = f2bf(r1); o.z = f2bf(r2); o.w = f2bf(r3);
            *(ushort4*)&Y[(size_t)n * (size_t)M + m0] = o;
        }
    }
}

// ---------------- bf16 MFMA GEMM, 128x64 tile (fp32 out), BK=64, double-buffered ----------------
// 2 blocks/CU at grid (2,256): hides the per-block barrier drains FFN2 suffers at 1/CU.
template <int K>
__global__ __launch_bounds__(256)
void mfma_gemm_n64_kernel(const u16* __restrict__ A, const u16* __restrict__ Bt,
                          const float* __restrict__ bias, float* __restrict__ Y, int M) {
    __shared__ __align__(16) u16 As[2][128][64];
    __shared__ __align__(16) u16 Bs[2][64][64];
    constexpr int NIT = K / 64;
    int mt = blockIdx.x, nt = blockIdx.y;
    const u16* Ab = A + (size_t)mt * 128 * K;
    const u16* Bb = Bt + (size_t)nt * 64 * K;
    int t = threadIdx.x;
    int w = t >> 6, lane = t & 63;
    int q = lane >> 4, idx = lane & 15;
    int wr = (w >> 1) * 64, wc = (w & 1) * 32;
    int srow = lane >> 3;
    int gch = (lane & 7) ^ srow;

    f32x4 acc[4][2];
#pragma unroll
    for (int i = 0; i < 4; ++i)
#pragma unroll
        for (int j = 0; j < 2; ++j) { f32x4 z = {0.f, 0.f, 0.f, 0.f}; acc[i][j] = z; }

#define ISSUE_LOADS64(buf, k0)                                                            \
    {                                                                                     \
        _Pragma("unroll")                                                                 \
        for (int p = 0; p < 4; ++p) {                                                     \
            int r = w * 32 + p * 8 + srow;                                                \
            __builtin_amdgcn_global_load_lds(                                             \
                (const __attribute__((address_space(1))) void*)(Ab + (size_t)r * K + (k0) + gch * 8), \
                (__attribute__((address_space(3))) void*)(&As[buf][w * 32 + p * 8][0]),   \
                16, 0, 0);                                                                \
        }                                                                                 \
        _Pragma("unroll")                                                                 \
        for (int p = 0; p < 2; ++p) {                                                     \
            int r = w * 16 + p * 8 + srow;                                                \
            __builtin_amdgcn_global_load_lds(                                             \
                (const __attribute__((address_space(1))) void*)(Bb + (size_t)r * K + (k0) + gch * 8), \
                (__attribute__((address_space(3))) void*)(&Bs[buf][w * 16 + p * 8][0]),   \
                16, 0, 0);                                                                \
        }                                                                                 \
    }

    ISSUE_LOADS64(0, 0)
    for (int ki = 0; ki < NIT; ++ki) {
        int cur = ki & 1;
        __syncthreads();
        if (ki + 1 < NIT) ISSUE_LOADS64(cur ^ 1, (ki + 1) * 64)
#pragma unroll
        for (int h = 0; h < 2; ++h) {
            bf16x8 af[4], bfr[2];
#pragma unroll
            for (int i = 0; i < 4; ++i)
                af[i] = *(const bf16x8*)&As[cur][wr + i * 16 + idx][(((q + 4 * h) ^ (idx & 7)) * 8)];
#pragma unroll
            for (int j = 0; j < 2; ++j)
                bfr[j] = *(const bf16x8*)&Bs[cur][wc + j * 16 + idx][(((q + 4 * h) ^ (idx & 7)) * 8)];
#pragma unroll
            for (int i = 0; i < 4; ++i)
#pragma unroll
                for (int j = 0; j < 2; ++j)
                    acc[i][j] = __builtin_amdgcn_mfma_f32_16x16x32_bf16(af[i], bfr[j], acc[i][j], 0, 0, 0);
        }
    }
#undef ISSUE_LOADS64

    // fp32 output Y[b][m][n]
#pragma unroll
    for (int i = 0; i < 4; ++i) {
        int m0 = mt * 128 + wr + i * 16 + q * 4;
        float b0 = bias[m0], b1 = bias[m0 + 1], b2 = bias[m0 + 2], b3 = bias[m0 + 3];
#pragma unroll
        for (int j = 0; j < 2; ++j) {
            int ng = nt * 64 + wc + j * 16 + idx;
            int bb = ng >> 10, nn = ng & 1023;
            f32x4 v = acc[i][j];
            float* p = Y + ((size_t)bb * M + m0) * NP + nn;
            p[0]      = v.x + b0;
            p[NP]     = v.y + b1;
            p[2 * NP] = v.z + b2;
            p[3 * NP] = v.w + b3;
        }
    }
}

extern "C" void kernel_launch(void* const* d_in, const int* in_sizes, int n_in,
                              void* d_out, int out_size, void* d_ws, size_t ws_size,
                              hipStream_t stream) {
    const float* x      = (const float*)d_in[0];
    const float* fc1_w  = (const float*)d_in[1];
    const float* fc1_b  = (const float*)d_in[2];
    const float* fc2_w  = (const float*)d_in[3];
    const float* fc2_b  = (const float*)d_in[4];
    const float* qkv_w  = (const float*)d_in[5];
    const float* qkv_b  = (const float*)d_in[6];
    const float* proj_w = (const float*)d_in[7];
    const float* proj_b = (const float*)d_in[8];
    const float* ffn1_w = (const float*)d_in[9];
    const float* ffn1_b = (const float*)d_in[10];
    const float* ffn2_w = (const float*)d_in[11];
    const float* ffn2_b = (const float*)d_in[12];
    float* out = (float*)d_out;

    // layout: [w1b 512K][w2b 512K][ygt 8M][ht 32M]; pre-FFN buffers overlap ht (dead by FFN1)
    u16* w1b = (u16*)d_ws;
    u16* w2b = w1b + 262144;
    u16* ygt = w2b + 262144;                         // [b*1024][256] bf16
    u16* ht  = ygt + (size_t)BB * NP * CC;           // [b*1024][1024] bf16
    float* sig    = (float*)ht;                      // 16 KB
    float* s_mean = sig + BB * CC;                   // 16 KB
    u16* Qt = (u16*)(s_mean + BB * CC);              // 1 MB
    u16* Kt = Qt + (size_t)BB * NP * 32;             // 1 MB
    u16* Vb = Kt + (size_t)BB * NP * 32;             // 1 MB

    se_mean_conv_kernel<<<BB * CC + 512, 256, 0, stream>>>(x, s_mean, ffn1_w, w1b, ffn2_w, w2b);
    se_mlp_kernel<<<BB, 256, 0, stream>>>(s_mean, fc1_w, fc1_b, fc2_w, fc2_b, sig);
    scale_transpose_qkv_kernel<<<dim3(16, 4, BB), 256, 0, stream>>>(
        x, sig, qkv_w, qkv_b, ygt, Qt, Kt, Vb);
    attn_mfma_kernel<<<BB * 64, 256, 0, stream>>>(Qt, Kt, Vb, proj_w, proj_b, ygt);

    // FFN1: ht[nflat][1024] bf16 (ReLU) = ffn1_w(1024x256) @ ygt
    mfma_gemm_kernel<256, true><<<dim3(8, 128), 256, 0, stream>>>(
        w1b, ygt, ffn1_b, ht, 1024);
    // FFN2: out[b][256][1024] fp32 = ffn2_w(256x1024) @ ht  (128x64 tiles, 2 blocks/CU)
    mfma_gemm_n64_kernel<1024><<<dim3(2, 256), 256, 0, stream>>>(
        w2b, ht, ffn2_b, out, 256);
}